// Round 10
// baseline (334.316 us; speedup 1.0000x reference)
//
#include <hip/hip_runtime.h>
#include <hip/hip_bf16.h>

typedef __bf16 bf16x8 __attribute__((ext_vector_type(8)));
typedef float f32x4 __attribute__((ext_vector_type(4)));
typedef unsigned short ushort_t;
typedef unsigned int uint_t;

#define HN 16
#define LSEQ 256
#define DD 1024
#define BB 4
#define SS 4096
#define MROWS (BB * SS) /* 16384 */
#define BHN (BB * HN)   /* 64 */

#define AS1 __attribute__((address_space(1)))
#define AS3 __attribute__((address_space(3)))

__device__ __forceinline__ ushort_t f2bf(float f) {
  uint_t u = __builtin_bit_cast(uint_t, f);
  u += 0x7fffu + ((u >> 16) & 1u); // RNE
  return (ushort_t)(u >> 16);
}
__device__ __forceinline__ uint_t cvtpk(float lo, float hi) {
  uint_t r;
  asm("v_cvt_pk_bf16_f32 %0, %1, %2" : "=v"(r) : "v"(lo), "v"(hi));
  return r;
}

// ---------- weight transpose x4: W fp32 [K][N] -> WT bf16 [N][K], packed ----------
__global__ __launch_bounds__(256) void transpose_w4(const float* __restrict__ W0,
                                                    const float* __restrict__ W1,
                                                    const float* __restrict__ W2,
                                                    const float* __restrict__ W3,
                                                    ushort_t* __restrict__ WT) {
  __shared__ float tile[32][33];
  const int z = blockIdx.z;
  const float* W = (z == 0) ? W0 : (z == 1) ? W1 : (z == 2) ? W2 : W3;
  ushort_t* dst = WT + (long)z * 1048576;
  const int tx = threadIdx.x, ty = threadIdx.y;
  const int bn = blockIdx.x * 32, bk = blockIdx.y * 32;
#pragma unroll
  for (int j = 0; j < 32; j += 8)
    tile[ty + j][tx] = W[(long)(bk + ty + j) * DD + bn + tx];
  __syncthreads();
#pragma unroll
  for (int j = 0; j < 32; j += 8)
    dst[(long)(bn + ty + j) * DD + bk + tx] = f2bf(tile[tx][ty + j]);
}

// ---------- vh transpose per (b,h): [256][1024] -> [1024][256] bf16 ----------
__global__ __launch_bounds__(256) void transpose_v(const ushort_t* __restrict__ vh,
                                                   ushort_t* __restrict__ vhT) {
  __shared__ ushort_t tile[32][33];
  const int tx = threadIdx.x, ty = threadIdx.y;
  const long zo = (long)blockIdx.z * (LSEQ * DD);
  const ushort_t* src = vh + zo;
  ushort_t* dst = vhT + zo;
  const int bd = blockIdx.x * 32; // d
  const int bl = blockIdx.y * 32; // l
#pragma unroll
  for (int j = 0; j < 32; j += 8)
    tile[ty + j][tx] = src[(long)(bl + ty + j) * DD + bd + tx];
  __syncthreads();
#pragma unroll
  for (int j = 0; j < 32; j += 8)
    dst[(long)(bd + ty + j) * LSEQ + bl + tx] = tile[tx][ty + j];
}

// ---------- fused scores + mask + softmax ----------
__global__ __launch_bounds__(256, 2) void score_sm(const ushort_t* __restrict__ qh,
                                                   const ushort_t* __restrict__ kh,
                                                   const int* __restrict__ mask,
                                                   ushort_t* __restrict__ att) {
  __shared__ char smemraw[81920];
  ushort_t* sA = (ushort_t*)smemraw;
  ushort_t* sB = (ushort_t*)(smemraw + 16384);
  float* Sf = (float*)smemraw;

  const int orig = blockIdx.x;
  const int wgid = (orig & 7) * 32 + (orig >> 3);
  const int bh = wgid >> 2, rb = wgid & 3;
  const int b = bh >> 4;
  const ushort_t* A = qh + ((long)bh * 256 + rb * 64) * 1024;
  const ushort_t* Bk = kh + (long)bh * 256 * 1024;

  const int t = threadIdx.x, lane = t & 63, wid = t >> 6;
  const int fr = lane & 15, q = lane >> 4;
  const int wc = wid * 64;
  const int sw0 = (q ^ (fr & 7)) * 8;
  const int sw1 = ((4 + q) ^ (fr & 7)) * 8;

  int srcAo[2], dstA[2], srcBo[8], dstB[8];
#pragma unroll
  for (int i = 0; i < 2; ++i) {
    const int c = i * 256 + t, row = c >> 3, gc = (c & 7) ^ (row & 7);
    srcAo[i] = row * 1024 + gc * 8;
    dstA[i] = (i * 256 + (t & 192)) * 8;
  }
#pragma unroll
  for (int i = 0; i < 8; ++i) {
    const int c = i * 256 + t, row = c >> 3, gc = (c & 7) ^ (row & 7);
    srcBo[i] = row * 1024 + gc * 8;
    dstB[i] = (i * 256 + (t & 192)) * 8;
  }

  auto stage = [&](int buf, int kt) {
    const int ko = kt * 64;
#pragma unroll
    for (int i = 0; i < 2; ++i)
      __builtin_amdgcn_global_load_lds(
          (const AS1 void*)(A + srcAo[i] + ko),
          (AS3 void*)(sA + buf * 4096 + dstA[i]), 16, 0, 0);
#pragma unroll
    for (int i = 0; i < 8; ++i)
      __builtin_amdgcn_global_load_lds(
          (const AS1 void*)(Bk + srcBo[i] + ko),
          (AS3 void*)(sB + buf * 16384 + dstB[i]), 16, 0, 0);
  };

  f32x4 acc[4][4];
#pragma unroll
  for (int m = 0; m < 4; ++m)
#pragma unroll
    for (int n = 0; n < 4; ++n) acc[m][n] = (f32x4){0.f, 0.f, 0.f, 0.f};

  stage(0, 0);
  __syncthreads();
  int cur = 0;
  for (int kt = 0; kt < 16; ++kt) {
    if (kt < 15) stage(cur ^ 1, kt + 1);
    bf16x8 af[4][2], bfv[4][2];
    const ushort_t* bA = sA + cur * 4096;
    const ushort_t* bB = sB + cur * 16384;
#pragma unroll
    for (int m = 0; m < 4; ++m) {
      af[m][0] = *(const bf16x8*)(bA + (m * 16 + fr) * 64 + sw0);
      af[m][1] = *(const bf16x8*)(bA + (m * 16 + fr) * 64 + sw1);
    }
#pragma unroll
    for (int n = 0; n < 4; ++n) {
      bfv[n][0] = *(const bf16x8*)(bB + (wc + n * 16 + fr) * 64 + sw0);
      bfv[n][1] = *(const bf16x8*)(bB + (wc + n * 16 + fr) * 64 + sw1);
    }
#pragma unroll
    for (int m = 0; m < 4; ++m)
#pragma unroll
      for (int n = 0; n < 4; ++n) {
        acc[m][n] = __builtin_amdgcn_mfma_f32_16x16x32_bf16(af[m][0], bfv[n][0], acc[m][n], 0, 0, 0);
        acc[m][n] = __builtin_amdgcn_mfma_f32_16x16x32_bf16(af[m][1], bfv[n][1], acc[m][n], 0, 0, 0);
      }
    __syncthreads();
    cur ^= 1;
  }

#pragma unroll
  for (int m = 0; m < 4; ++m)
#pragma unroll
    for (int n = 0; n < 4; ++n)
#pragma unroll
      for (int r = 0; r < 4; ++r)
        Sf[(m * 16 + q * 4 + r) * 256 + wc + n * 16 + fr] = acc[m][n][r];
  __syncthreads();

#pragma unroll 2
  for (int i = 0; i < 16; ++i) {
    const int row = wid * 16 + i;
    const int gl = rb * 64 + row;
    const f32x4 sv = *(const f32x4*)&Sf[row * 256 + lane * 4];
    const int4 mv = *(const int4*)&mask[((long)b * 256 + gl) * 256 + lane * 4];
    float s[4];
    s[0] = (mv.x == 0) ? 1e-9f : sv[0] * 0.03125f;
    s[1] = (mv.y == 0) ? 1e-9f : sv[1] * 0.03125f;
    s[2] = (mv.z == 0) ? 1e-9f : sv[2] * 0.03125f;
    s[3] = (mv.w == 0) ? 1e-9f : sv[3] * 0.03125f;
    float mx = fmaxf(fmaxf(s[0], s[1]), fmaxf(s[2], s[3]));
#pragma unroll
    for (int off = 32; off; off >>= 1) mx = fmaxf(mx, __shfl_xor(mx, off));
    float e[4], sum = 0.f;
#pragma unroll
    for (int j = 0; j < 4; ++j) {
      e[j] = __expf(s[j] - mx);
      sum += e[j];
    }
#pragma unroll
    for (int off = 32; off; off >>= 1) sum += __shfl_xor(sum, off);
    const float inv = 1.0f / sum;
    ushort4 o;
    o.x = f2bf(e[0] * inv);
    o.y = f2bf(e[1] * inv);
    o.z = f2bf(e[2] * inv);
    o.w = f2bf(e[3] * inv);
    *(ushort4*)&att[((long)bh * 256 + gl) * 256 + lane * 4] = o;
  }
}

// ---------- 128^2 TN GEMM (batched PV), bf16 pv-permute store ----------
__global__ __launch_bounds__(256, 2) void gemm_tn(const ushort_t* __restrict__ Ab,
                                                  const ushort_t* __restrict__ Btp,
                                                  void* __restrict__ Cp, int K, int ldA,
                                                  int ldB, int ldC, long batchA,
                                                  long batchB, long batchC) {
  __shared__ ushort_t smem[16384];
  ushort_t* sA = smem;
  ushort_t* sB = smem + 8192;

  const int bx = blockIdx.x, by = blockIdx.y, z = blockIdx.z;
  const int rowBase = by * 128;
  const int colBase = bx * 128;

  const int t = threadIdx.x;
  const int lane = t & 63;
  const int wid = t >> 6;
  const int wr = (wid >> 1) * 64;
  const int wc = (wid & 1) * 64;
  const int fr = lane & 15;
  const int fk = (lane >> 4) * 8;

  const ushort_t* Atile = Ab + batchA * z + (long)rowBase * ldA;
  const ushort_t* Btile = Btp + batchB * z + (long)colBase * ldB;

  f32x4 acc[4][4];
#pragma unroll
  for (int m = 0; m < 4; ++m)
#pragma unroll
    for (int n = 0; n < 4; ++n) acc[m][n] = (f32x4){0.f, 0.f, 0.f, 0.f};

  const int NT = K >> 5;

  auto stageAB = [&](int buf, int kt) {
    const long ko = (long)kt * 32;
#pragma unroll
    for (int i = 0; i < 2; ++i) {
      const int c = i * 256 + t;
      const int cw = i * 256 + (t & 192);
      __builtin_amdgcn_global_load_lds(
          (const AS1 void*)(Atile + (long)(c >> 2) * ldA + ko + (c & 3) * 8),
          (AS3 void*)(sA + buf * 4096 + cw * 8), 16, 0, 0);
      __builtin_amdgcn_global_load_lds(
          (const AS1 void*)(Btile + (long)(c >> 2) * ldB + ko + (c & 3) * 8),
          (AS3 void*)(sB + buf * 4096 + cw * 8), 16, 0, 0);
    }
  };

  stageAB(0, 0);
  __syncthreads();

  int cur = 0;
  for (int kt = 0; kt < NT; ++kt) {
    if (kt + 1 < NT) stageAB(cur ^ 1, kt + 1);

    bf16x8 af[4], bfv[4];
    const ushort_t* baseA = sA + cur * 4096 + fk;
    const ushort_t* baseB = sB + cur * 4096 + fk;
#pragma unroll
    for (int m = 0; m < 4; ++m) af[m] = *(const bf16x8*)(baseA + (wr + m * 16 + fr) * 32);
#pragma unroll
    for (int n = 0; n < 4; ++n) bfv[n] = *(const bf16x8*)(baseB + (wc + n * 16 + fr) * 32);

#pragma unroll
    for (int m = 0; m < 4; ++m)
#pragma unroll
      for (int n = 0; n < 4; ++n)
        acc[m][n] = __builtin_amdgcn_mfma_f32_16x16x32_bf16(af[m], bfv[n], acc[m][n], 0, 0, 0);

    __syncthreads();
    cur ^= 1;
  }

  const int rq = (lane >> 4) * 4;
#pragma unroll
  for (int m = 0; m < 4; ++m)
#pragma unroll
    for (int n = 0; n < 4; ++n)
#pragma unroll
      for (int r = 0; r < 4; ++r)
        smem[(wr + m * 16 + rq + r) * 128 + wc + n * 16 + fr] = f2bf(acc[m][n][r]);
  __syncthreads();
  ushort_t* Cb = (ushort_t*)Cp;
  const int c8 = (lane & 15) * 8;
#pragma unroll
  for (int i = 0; i < 8; ++i) {
    const int row = i * 16 + wid * 4 + (lane >> 4);
    const uint4 val = *(const uint4*)(smem + row * 128 + c8);
    const int l = rowBase + row;
    const int orow = ((z >> 4) << 12) + l * 16 + (z & 15); // b*4096 + l*16 + h
    *(uint4*)(Cb + (long)orow * 1024 + colBase + c8) = val;
  }
}

#define SBAR() asm volatile("s_barrier" ::: "memory")
#define LGKM0() asm volatile("s_waitcnt lgkmcnt(0)" ::: "memory")
#define VM(N) asm volatile("s_waitcnt vmcnt(" #N ")" ::: "memory")
#define PH_OPEN() SBAR(); LGKM0(); __builtin_amdgcn_s_setprio(1)
#define PH_CLOSE() __builtin_amdgcn_s_setprio(0); SBAR()

// ---------- 256^2 8-phase TN GEMM, bf16 A (final x@Wo) — proven round-9 version ----------
template <int SMODE>
__global__ __launch_bounds__(512, 1) void gemm256(const ushort_t* __restrict__ A0,
                                                  const ushort_t* __restrict__ Btp,
                                                  void* __restrict__ Cp) {
  __shared__ ushort_t sm[65536];

  const int orig = blockIdx.x;
  const int cpx = (int)gridDim.x >> 3;
  const int wgid = (orig & 7) * cpx + (orig >> 3);
  const int by = wgid >> 2, bx = wgid & 3;
  const int rowBase = by * 256, colBase = bx * 256;

  const ushort_t* Ab = A0;
  const ushort_t* Bt = Btp;

  const int t = threadIdx.x;
  const int lane = t & 63;
  const int wid = t >> 6;
  const int wm = wid >> 2;
  const int wn = wid & 3;
  const int fr = lane & 15;
  const int q = lane >> 4;

  const int sw0 = ((q ^ (fr & 7)) * 8);
  const int sw1 = (((4 + q) ^ (fr & 7)) * 8);
  const int aoff0 = fr * 64 + sw0;
  const int aoff1 = fr * 64 + sw1;
  const int bbase = ((wn & 1) * 64 + fr) * 64;
  const int boff0 = bbase + sw0;
  const int boff1 = bbase + sw1;

  const ushort_t* srcA[2][2];
  const ushort_t* srcB[2][2];
  int ldsoff[2];
#pragma unroll
  for (int i = 0; i < 2; ++i) {
    const int c = i * 512 + t;
    const int rowc = c >> 3;
    const int gc = (c & 7) ^ (rowc & 7);
    srcA[0][i] = Ab + (long)(rowBase + rowc) * 1024 + gc * 8;
    srcA[1][i] = Ab + (long)(rowBase + 128 + rowc) * 1024 + gc * 8;
    srcB[0][i] = Bt + (long)(colBase + rowc) * 1024 + gc * 8;
    srcB[1][i] = Bt + (long)(colBase + 128 + rowc) * 1024 + gc * 8;
    ldsoff[i] = (c & ~63) * 8;
  }

#define STAGE(kind, h, T)                                                                   \
  do {                                                                                      \
    ushort_t* _d = sm + ((kind) ? 32768 : 0) + ((T) & 1) * 16384 + (h) * 8192;              \
    const ushort_t* _s0 = ((kind) ? srcB[h][0] : srcA[h][0]) + (long)(T) * 64;              \
    __builtin_amdgcn_global_load_lds((const AS1 void*)_s0,                                  \
                                     (AS3 void*)(_d + ldsoff[0]), 16, 0, 0);                \
    const ushort_t* _s1 = ((kind) ? srcB[h][1] : srcA[h][1]) + (long)(T) * 64;              \
    __builtin_amdgcn_global_load_lds((const AS1 void*)_s1,                                  \
                                     (AS3 void*)(_d + ldsoff[1]), 16, 0, 0);                \
  } while (0)

  f32x4 acc[8][4];
#pragma unroll
  for (int m = 0; m < 8; ++m)
#pragma unroll
    for (int n = 0; n < 4; ++n) acc[m][n] = (f32x4){0.f, 0.f, 0.f, 0.f};

  bf16x8 af[4][2], bf0[2][2], bf1[2][2];

#define LDA4(dbuf, msub)                                                         \
  do {                                                                           \
    const ushort_t* _b = sm + (dbuf)*16384 + wm * 8192 + (msub)*4096;            \
    _Pragma("unroll") for (int m2 = 0; m2 < 4; ++m2) {                           \
      af[m2][0] = *(const bf16x8*)(_b + m2 * 1024 + aoff0);                      \
      af[m2][1] = *(const bf16x8*)(_b + m2 * 1024 + aoff1);                      \
    }                                                                            \
  } while (0)

#define LDB2(dbuf, nsub, bfv)                                                    \
  do {                                                                           \
    const ushort_t* _b = sm + 32768 + (dbuf)*16384 + (wn >> 1) * 8192 + (nsub)*2048; \
    _Pragma("unroll") for (int n2 = 0; n2 < 2; ++n2) {                           \
      bfv[n2][0] = *(const bf16x8*)(_b + n2 * 1024 + boff0);                     \
      bfv[n2][1] = *(const bf16x8*)(_b + n2 * 1024 + boff1);                     \
    }                                                                            \
  } while (0)

#define MMQ(msub, nsub, bfv)                                                     \
  do {                                                                           \
    _Pragma("unroll") for (int m2 = 0; m2 < 4; ++m2)                             \
        _Pragma("unroll") for (int n2 = 0; n2 < 2; ++n2) {                       \
      acc[(msub)*4 + m2][(nsub)*2 + n2] = __builtin_amdgcn_mfma_f32_16x16x32_bf16( \
          af[m2][0], bfv[n2][0], acc[(msub)*4 + m2][(nsub)*2 + n2], 0, 0, 0);    \
      acc[(msub)*4 + m2][(nsub)*2 + n2] = __builtin_amdgcn_mfma_f32_16x16x32_bf16( \
          af[m2][1], bfv[n2][1], acc[(msub)*4 + m2][(nsub)*2 + n2], 0, 0, 0);    \
    }                                                                            \
  } while (0)

  const int NT = 16;
  const int NI = 8;

  STAGE(0, 0, 0);
  STAGE(0, 1, 0);
  STAGE(1, 0, 0);
  STAGE(1, 1, 0);
  STAGE(0, 0, 1);
  STAGE(0, 1, 1);
  STAGE(1, 0, 1);
  STAGE(1, 1, 1);
  VM(8);
  SBAR();

  for (int it = 0; it < NI - 1; ++it) {
    const int T0 = 2 * it;
    LDA4(0, 0);
    LDB2(0, 0, bf0);
    PH_OPEN(); MMQ(0, 0, bf0); PH_CLOSE();
    LDB2(0, 1, bf1);
    PH_OPEN(); MMQ(0, 1, bf1); PH_CLOSE();
    LDA4(0, 1);
    STAGE(1, 0, T0 + 2);
    STAGE(1, 1, T0 + 2);
    PH_OPEN(); MMQ(1, 1, bf1); PH_CLOSE();
    STAGE(0, 0, T0 + 2);
    STAGE(0, 1, T0 + 2);
    SBAR();
    __builtin_amdgcn_s_setprio(1);
    MMQ(1, 0, bf0);
    __builtin_amdgcn_s_setprio(0);
    VM(8);
    SBAR();
    LDA4(1, 0);
    LDB2(1, 0, bf0);
    PH_OPEN(); MMQ(0, 0, bf0); PH_CLOSE();
    LDB2(1, 1, bf1);
    PH_OPEN(); MMQ(0, 1, bf1); PH_CLOSE();
    LDA4(1, 1);
    STAGE(1, 0, T0 + 3);
    STAGE(1, 1, T0 + 3);
    PH_OPEN(); MMQ(1, 1, bf1); PH_CLOSE();
    STAGE(0, 0, T0 + 3);
    STAGE(0, 1, T0 + 3);
    SBAR();
    __builtin_amdgcn_s_setprio(1);
    MMQ(1, 0, bf0);
    __builtin_amdgcn_s_setprio(0);
    VM(8);
    SBAR();
  }

  {
    LDA4(0, 0);
    LDB2(0, 0, bf0);
    PH_OPEN(); MMQ(0, 0, bf0); PH_CLOSE();
    LDB2(0, 1, bf1);
    PH_OPEN(); MMQ(0, 1, bf1); PH_CLOSE();
    LDA4(0, 1);
    PH_OPEN(); MMQ(1, 1, bf1); PH_CLOSE();
    SBAR();
    __builtin_amdgcn_s_setprio(1);
    MMQ(1, 0, bf0);
    __builtin_amdgcn_s_setprio(0);
    VM(0);
    SBAR();
    LDA4(1, 0);
    LDB2(1, 0, bf0);
    PH_OPEN(); MMQ(0, 0, bf0); PH_CLOSE();
    LDB2(1, 1, bf1);
    PH_OPEN(); MMQ(0, 1, bf1); PH_CLOSE();
    LDA4(1, 1);
    PH_OPEN(); MMQ(1, 1, bf1); PH_CLOSE();
    SBAR();
    MMQ(1, 0, bf0);
    SBAR();
  }

  const int rq = q * 4;
  if constexpr (SMODE == 0) {
    float* Cf = (float*)Cp;
#pragma unroll
    for (int m = 0; m < 8; ++m)
#pragma unroll
      for (int n = 0; n < 4; ++n)
#pragma unroll
        for (int r = 0; r < 4; ++r) {
          const int row = rowBase + wm * 128 + m * 16 + rq + r;
          const int col = colBase + wn * 64 + n * 16 + fr;
          Cf[(long)row * 1024 + col] = acc[m][n][r];
        }
  }
#undef STAGE
#undef LDA4
#undef LDB2
#undef MMQ
}

// ---------- 256^2 TN GEMM, A read as FP32 from HBM, LDS-side convert ----------
// z-batched: q,k,v fp32 [16384][1024] -> qh/kh/vh bf16 proj-permuted. grid 768x512.
// LDS: A fp32 dbuf 2x32KB (BK=32, rows 128B, XOR(fr&7) chunk swizzle) at bytes [0,64K);
//      B bf16 dbuf 2x32KB (B-tile = 256xK64, rows 128B, proven layout) at [64K,128K).
// 4 phases per K-tile T (32 K-elems). B-tile b=T>>1. Ledger (4 loads/stage):
//  even T: Ph1 +B(b+1); Ph4 +A(T+2); gate VM(8) drains A(T+1) [4-phase cover]
//  odd  T: Ph4 +A(T+2); gate VM(4) drains B(b+1)+A(T+2)... (leaves A(T+3))
// A(T+2) staged at Ph4 into dbuf T&1 — safe: all A(T) reads complete by Ph3-close.
__global__ __launch_bounds__(512, 1) void gemm256f32a(const float* __restrict__ A0,
                                                      const float* __restrict__ A1,
                                                      const float* __restrict__ A2,
                                                      const ushort_t* __restrict__ Btp,
                                                      ushort_t* __restrict__ Cp) {
  __shared__ ushort_t sm[65536]; // 128 KiB
  char* smb = (char*)sm;

  const int orig = blockIdx.x;
  const int cpx = (int)gridDim.x >> 3; // 96
  const int wgid = (orig & 7) * cpx + (orig >> 3);
  const int z = wgid >> 8;
  const int tile = wgid & 255;
  const int by = tile >> 2, bx = tile & 3;
  const int rowBase = by * 256, colBase = bx * 256;

  const float* Af = (z == 0) ? A0 : (z == 1) ? A1 : A2;
  const ushort_t* Bt = Btp + (long)z * 1048576;

  const int t = threadIdx.x;
  const int lane = t & 63;
  const int wid = t >> 6;
  const int wm = wid >> 2; // 0..1
  const int wn = wid & 3;  // 0..3
  const int fr = lane & 15;
  const int q = lane >> 4;

  // A fragment slot byte-offsets within a 128B row (two 16B fp32 slots)
  const int sA0 = ((2 * q) ^ (fr & 7)) * 16;
  const int sA1 = ((2 * q + 1) ^ (fr & 7)) * 16;
  // B fragment slot elem-offsets per tile parity
  const int sB0 = ((q) ^ (fr & 7)) * 8;
  const int sB1 = ((4 + q) ^ (fr & 7)) * 8;

  // staging precompute: A fp32 (4x16B chunks/thread/K-tile), B bf16 (4/thread/B-tile)
  const float* srcA[4];
  int ldsAu[4];
  const ushort_t* srcBt[4];
  int ldsBu[4];
#pragma unroll
  for (int i = 0; i < 4; ++i) {
    const int cA = i * 512 + t;
    const int rA = cA >> 3;
    const int gA = (cA & 7) ^ (rA & 7);
    srcA[i] = Af + (long)(rowBase + rA) * 1024 + gA * 4;
    ldsAu[i] = (cA & ~63) * 16; // bytes, wave-uniform
    const int cB = i * 512 + t;
    const int rB = cB >> 3;
    const int gB = (cB & 7) ^ (rB & 7);
    srcBt[i] = Bt + (long)(colBase + rB) * 1024 + gB * 8;
    ldsBu[i] = (cB & ~63) * 8; // elems, wave-uniform
  }

#define SAF4(T, d)                                                                          \
  do {                                                                                      \
    _Pragma("unroll") for (int _i = 0; _i < 4; ++_i)                                        \
        __builtin_amdgcn_global_load_lds((const AS1 void*)(srcA[_i] + (long)(T) * 32),      \
                                         (AS3 void*)(smb + (d)*32768 + ldsAu[_i]), 16, 0, 0); \
  } while (0)

#define SBF(b, bb)                                                                          \
  do {                                                                                      \
    _Pragma("unroll") for (int _i = 0; _i < 4; ++_i)                                        \
        __builtin_amdgcn_global_load_lds((const AS1 void*)(srcBt[_i] + (long)(b) * 64),     \
                                         (AS3 void*)(sm + 32768 + (bb)*16384 + ldsBu[_i]),  \
                                         16, 0, 0);                                         \
  } while (0)

  f32x4 acc[8][4];
#pragma unroll
  for (int m = 0; m < 8; ++m)
#pragma unroll
    for (int n = 0; n < 4; ++n) acc[m][n] = (f32x4){0.f, 0.f, 0.f, 0.f};

  bf16x8 af[4], bf0[2], bf1[2];

#define LDA4F(d, msub)                                                                      \
  do {                                                                                      \
    _Pragma("unroll") for (int m2 = 0; m2 < 4; ++m2) {                                      \
      const char* _p = smb + (d)*32768 + (wm * 128 + (msub)*64 + m2 * 16 + fr) * 128;       \
      const float4 _u = *(const float4*)(_p + sA0);                                         \
      const float4 _v = *(const float4*)(_p + sA1);                                         \
      uint4 _w;                                                                             \
      _w.x = cvtpk(_u.x, _u.y);                                                             \
      _w.y = cvtpk(_u.z, _u.w);                                                             \
      _w.z = cvtpk(_v.x, _v.y);                                                             \
      _w.w = cvtpk(_v.z, _v.w);                                                             \
      af[m2] = __builtin_bit_cast(bf16x8, _w);                                              \
    }                                                                                       \
  } while (0)

#define LDB2F(bb, SBOFF, nsub, bfv)                                                         \
  do {                                                                                      \
    _Pragma("unroll") for (int n2 = 0; n2 < 2; ++n2) {                                      \
      const int _row = (wn >> 1) * 128 + (wn & 1) * 64 + (nsub)*32 + n2 * 16 + fr;          \
      bfv[n2] = *(const bf16x8*)(sm + 32768 + (bb)*16384 + _row * 64 + (SBOFF));            \
    }                                                                                       \
  } while (0)

#define MMQF(msub, nsub, bfv)                                                               \
  do {                                                                                      \
    _Pragma("unroll") for (int m2 = 0; m2 < 4; ++m2)                                        \
        _Pragma("unroll") for (int n2 = 0; n2 < 2; ++n2) acc[(msub)*4 + m2][(nsub)*2 + n2] = \
        __builtin_amdgcn_mfma_f32_16x16x32_bf16(af[m2], bfv[n2],                            \
                                                acc[(msub)*4 + m2][(nsub)*2 + n2], 0, 0, 0); \
  } while (0)

  // even-T iteration: reads (d,bb,sB0); stages B(b+1)->bdst @Ph1, A(T+2)->d @Ph4; gate VM(8)
#define ITER_E(T, d, bb, bdst)                                                              \
  do {                                                                                      \
    LDA4F(d, 0);                                                                            \
    LDB2F(bb, sB0, 0, bf0);                                                                 \
    SBF(((T) >> 1) + 1, bdst);                                                              \
    PH_OPEN(); MMQF(0, 0, bf0); PH_CLOSE();                                                 \
    LDB2F(bb, sB0, 1, bf1);                                                                 \
    PH_OPEN(); MMQF(0, 1, bf1); PH_CLOSE();                                                 \
    LDA4F(d, 1);                                                                            \
    PH_OPEN(); MMQF(1, 1, bf1); PH_CLOSE();                                                 \
    SAF4((T) + 2, d);                                                                       \
    SBAR();                                                                                 \
    __builtin_amdgcn_s_setprio(1);                                                          \
    MMQF(1, 0, bf0);                                                                        \
    __builtin_amdgcn_s_setprio(0);                                                          \
    VM(8);                                                                                  \
    SBAR();                                                                                 \
  } while (0)

  // odd-T iteration: reads (d,bb,sB1); stages A(T+2)->d @Ph4; gate VM(4)
#define ITER_O(T, d, bb)                                                                    \
  do {                                                                                      \
    LDA4F(d, 0);                                                                            \
    LDB2F(bb, sB1, 0, bf0);                                                                 \
    PH_OPEN(); MMQF(0, 0, bf0); PH_CLOSE();                                                 \
    LDB2F(bb, sB1, 1, bf1);                                                                 \
    PH_OPEN(); MMQF(0, 1, bf1); PH_CLOSE();                                                 \
    LDA4F(d, 1);                                                                            \
    PH_OPEN(); MMQF(1, 1, bf1); PH_CLOSE();                                                 \
    SAF4((T) + 2, d);                                                                       \
    SBAR();                                                                                 \
    __builtin_amdgcn_s_setprio(1);                                                          \
    MMQF(1, 0, bf0);                                                                        \
    __builtin_amdgcn_s_setprio(0);                                                          \
    VM(4);                                                                                  \
    SBAR();                                                                                 \
  } while (0)

  // prologue: B(0)[4] + A(0)[4] + A(1)[4]; VM(4) drains B(0),A(0); leaves A(1)
  SBF(0, 0);
  SAF4(0, 0);
  SAF4(1, 1);
  VM(4);
  SBAR();

  for (int u = 0; u < 7; ++u) {
    const int T0 = 4 * u;
    ITER_E(T0, 0, 0, 1);
    ITER_O(T0 + 1, 1, 0);
    ITER_E(T0 + 2, 0, 1, 0);
    ITER_O(T0 + 3, 1, 1);
  }
  ITER_E(28, 0, 0, 1); // stages B(15)->bb1, A(30)->d0
  ITER_O(29, 1, 0);    // stages A(31)->d1; gate drains B(15),A(30)

  { // peeled T=30: even pattern (d0, bb1, sB0), no stages; gate VM(0) drains A(31)
    LDA4F(0, 0);
    LDB2F(1, sB0, 0, bf0);
    PH_OPEN(); MMQF(0, 0, bf0); PH_CLOSE();
    LDB2F(1, sB0, 1, bf1);
    PH_OPEN(); MMQF(0, 1, bf1); PH_CLOSE();
    LDA4F(0, 1);
    PH_OPEN(); MMQF(1, 1, bf1); PH_CLOSE();
    SBAR();
    __builtin_amdgcn_s_setprio(1);
    MMQF(1, 0, bf0);
    __builtin_amdgcn_s_setprio(0);
    VM(0);
    SBAR();
  }
  { // peeled T=31: odd pattern (d1, bb1, sB1), pure compute
    LDA4F(1, 0);
    LDB2F(1, sB1, 0, bf0);
    PH_OPEN(); MMQF(0, 0, bf0); PH_CLOSE();
    LDB2F(1, sB1, 1, bf1);
    PH_OPEN(); MMQF(0, 1, bf1); PH_CLOSE();
    LDA4F(1, 1);
    PH_OPEN(); MMQF(1, 1, bf1); PH_CLOSE();
    SBAR();
    MMQF(1, 0, bf0);
    SBAR();
  }

  // epilogue: bf16 proj-permute via swizzled LDS C-tile (reuses whole sm)
  const int rq = q * 4;
#pragma unroll
  for (int m = 0; m < 8; ++m)
#pragma unroll
    for (int n = 0; n < 4; ++n)
#pragma unroll
      for (int r = 0; r < 4; ++r) {
        const int row = wm * 128 + m * 16 + rq + r;
        const int col = wn * 64 + n * 16 + fr;
        sm[row * 256 + (((col >> 3) ^ (row & 7)) * 8) + (col & 7)] = f2bf(acc[m][n][r]);
      }
  __syncthreads();
  ushort_t* Cb = Cp + (long)z * 16777216;
  const int cc = t & 31;
  const int r0 = t >> 5;
#pragma unroll
  for (int i = 0; i < 16; ++i) {
    const int row = r0 + i * 16;
    const uint4 val = *(const uint4*)(sm + row * 256 + ((cc ^ (row & 7)) * 8));
    const int grow = rowBase + row; // = b*4096 + s, s = l*16+h
    const int b = grow >> 12;
    const int s = grow & 4095;
    const int orow = ((b << 4) + (s & 15)) * 256 + (s >> 4); // (b*16+h)*256 + l
    *(uint4*)(Cb + (long)orow * 1024 + colBase + cc * 8) = val;
  }
#undef SAF4
#undef SBF
#undef LDA4F
#undef LDB2F
#undef MMQF
#undef ITER_E
#undef ITER_O
}

extern "C" void kernel_launch(void* const* d_in, const int* in_sizes, int n_in,
                              void* d_out, int out_size, void* d_ws, size_t ws_size,
                              hipStream_t stream) {
  const float* q = (const float*)d_in[0];
  const float* k = (const float*)d_in[1];
  const float* v = (const float*)d_in[2];
  const int* mask = (const int*)d_in[3];
  const float* Wq = (const float*)d_in[4];
  const float* Wk = (const float*)d_in[5];
  const float* Wv = (const float*)d_in[6];
  const float* Wo = (const float*)d_in[7];
  float* out = (float*)d_out;

  char* ws = (char*)d_ws;
  const size_t MB = 1024 * 1024;
  // layout (peak 176 MB): WT 0..8 | qh 8..40 | kh 40..72 | vh 72..104 | vhT 104..136
  //                       | att 136..144 | x 144..176
  ushort_t* WT = (ushort_t*)ws;
  ushort_t* qh = (ushort_t*)(ws + 8 * MB);
  ushort_t* kh = (ushort_t*)(ws + 40 * MB);
  ushort_t* vh = (ushort_t*)(ws + 72 * MB);
  ushort_t* vhT = (ushort_t*)(ws + 104 * MB);
  ushort_t* att = (ushort_t*)(ws + 136 * MB);
  ushort_t* x = (ushort_t*)(ws + 144 * MB);

  const dim3 tb(32, 8);
  transpose_w4<<<dim3(32, 32, 4), tb, 0, stream>>>(Wq, Wk, Wv, Wo, WT);

  // fused fp32-read projection: q,k,v -> qh,kh,vh (one 768-block dispatch, no cvt pass)
  gemm256f32a<<<768, 512, 0, stream>>>(q, k, v, WT, qh);

  transpose_v<<<dim3(32, 8, BHN), tb, 0, stream>>>(vh, vhT);
  score_sm<<<256, 256, 0, stream>>>(qh, kh, mask, att);
  gemm_tn<<<dim3(8, 2, BHN), 256, 0, stream>>>(att, vhT, x, 256, 256, 256, 1024,
                                               (long)65536, (long)262144, 0);
  gemm256<0><<<256, 512, 0, stream>>>(x, WT + (size_t)3145728, out);
}

// Round 11
// 257.879 us; speedup vs baseline: 1.2964x; 1.2964x over previous
//
#include <hip/hip_runtime.h>
#include <hip/hip_bf16.h>

typedef __bf16 bf16x8 __attribute__((ext_vector_type(8)));
typedef float f32x4 __attribute__((ext_vector_type(4)));
typedef unsigned short ushort_t;
typedef unsigned int uint_t;

#define HN 16
#define LSEQ 256
#define DD 1024
#define BB 4
#define SS 4096
#define MROWS (BB * SS) /* 16384 */
#define BHN (BB * HN)   /* 64 */

#define AS1 __attribute__((address_space(1)))
#define AS3 __attribute__((address_space(3)))

__device__ __forceinline__ ushort_t f2bf(float f) {
  uint_t u = __builtin_bit_cast(uint_t, f);
  u += 0x7fffu + ((u >> 16) & 1u); // RNE
  return (ushort_t)(u >> 16);
}
__device__ __forceinline__ uint_t pk2(float lo, float hi) {
  return (uint_t)f2bf(lo) | ((uint_t)f2bf(hi) << 16);
}

// ---------- fp32 -> bf16 bulk convert, up to 3 sources (z picks) ----------
__global__ __launch_bounds__(256) void cvt3(const float4* __restrict__ s0,
                                            const float4* __restrict__ s1,
                                            const float4* __restrict__ s2,
                                            uint4* __restrict__ out) {
  const int z = blockIdx.y;
  const float4* in = (z == 0) ? s0 : (z == 1) ? s1 : s2;
  const long i = (long)blockIdx.x * 256 + threadIdx.x;
  const float4 a = in[i * 2];
  const float4 b = in[i * 2 + 1];
  uint4 o;
  o.x = pk2(a.x, a.y);
  o.y = pk2(a.z, a.w);
  o.z = pk2(b.x, b.y);
  o.w = pk2(b.z, b.w);
  out[(long)z * 2097152 + i] = o;
}

// ---------- weight transpose x4: W fp32 [K][N] -> WT bf16 [N][K], packed ----------
__global__ __launch_bounds__(256) void transpose_w4(const float* __restrict__ W0,
                                                    const float* __restrict__ W1,
                                                    const float* __restrict__ W2,
                                                    const float* __restrict__ W3,
                                                    ushort_t* __restrict__ WT) {
  __shared__ float tile[32][33];
  const int z = blockIdx.z;
  const float* W = (z == 0) ? W0 : (z == 1) ? W1 : (z == 2) ? W2 : W3;
  ushort_t* dst = WT + (long)z * 1048576;
  const int tx = threadIdx.x, ty = threadIdx.y;
  const int bn = blockIdx.x * 32, bk = blockIdx.y * 32;
#pragma unroll
  for (int j = 0; j < 32; j += 8)
    tile[ty + j][tx] = W[(long)(bk + ty + j) * DD + bn + tx];
  __syncthreads();
#pragma unroll
  for (int j = 0; j < 32; j += 8)
    dst[(long)(bn + ty + j) * DD + bk + tx] = f2bf(tile[tx][ty + j]);
}

// ---------- fused scores + mask + softmax ----------
// per block: one (b,h), 64 q-rows, all 256 k-cols, K=1024. att bf16 out.
__global__ __launch_bounds__(256, 2) void score_sm(const ushort_t* __restrict__ qh,
                                                   const ushort_t* __restrict__ kh,
                                                   const int* __restrict__ mask,
                                                   ushort_t* __restrict__ att) {
  __shared__ char smemraw[81920]; // staging A 16KB + B 64KB; epilogue S 64KB aliases
  ushort_t* sA = (ushort_t*)smemraw;           // 2 x 4096 elems
  ushort_t* sB = (ushort_t*)(smemraw + 16384); // 2 x 16384 elems
  float* Sf = (float*)smemraw;                 // [64][256] fp32

  const int orig = blockIdx.x;
  const int wgid = (orig & 7) * 32 + (orig >> 3); // XCD-chunked, 256 % 8 == 0
  const int bh = wgid >> 2, rb = wgid & 3;
  const int b = bh >> 4;
  const ushort_t* A = qh + ((long)bh * 256 + rb * 64) * 1024;
  const ushort_t* Bk = kh + (long)bh * 256 * 1024;

  const int t = threadIdx.x, lane = t & 63, wid = t >> 6;
  const int fr = lane & 15, q = lane >> 4;
  const int wc = wid * 64;
  const int sw0 = (q ^ (fr & 7)) * 8;
  const int sw1 = ((4 + q) ^ (fr & 7)) * 8;

  int srcAo[2], dstA[2], srcBo[8], dstB[8];
#pragma unroll
  for (int i = 0; i < 2; ++i) {
    const int c = i * 256 + t, row = c >> 3, gc = (c & 7) ^ (row & 7);
    srcAo[i] = row * 1024 + gc * 8;
    dstA[i] = (i * 256 + (t & 192)) * 8;
  }
#pragma unroll
  for (int i = 0; i < 8; ++i) {
    const int c = i * 256 + t, row = c >> 3, gc = (c & 7) ^ (row & 7);
    srcBo[i] = row * 1024 + gc * 8;
    dstB[i] = (i * 256 + (t & 192)) * 8;
  }

  auto stage = [&](int buf, int kt) {
    const int ko = kt * 64;
#pragma unroll
    for (int i = 0; i < 2; ++i)
      __builtin_amdgcn_global_load_lds(
          (const AS1 void*)(A + srcAo[i] + ko),
          (AS3 void*)(sA + buf * 4096 + dstA[i]), 16, 0, 0);
#pragma unroll
    for (int i = 0; i < 8; ++i)
      __builtin_amdgcn_global_load_lds(
          (const AS1 void*)(Bk + srcBo[i] + ko),
          (AS3 void*)(sB + buf * 16384 + dstB[i]), 16, 0, 0);
  };

  f32x4 acc[4][4];
#pragma unroll
  for (int m = 0; m < 4; ++m)
#pragma unroll
    for (int n = 0; n < 4; ++n) acc[m][n] = (f32x4){0.f, 0.f, 0.f, 0.f};

  stage(0, 0);
  __syncthreads();
  int cur = 0;
  for (int kt = 0; kt < 16; ++kt) {
    if (kt < 15) stage(cur ^ 1, kt + 1);
    bf16x8 af[4][2], bfv[4][2];
    const ushort_t* bA = sA + cur * 4096;
    const ushort_t* bB = sB + cur * 16384;
#pragma unroll
    for (int m = 0; m < 4; ++m) {
      af[m][0] = *(const bf16x8*)(bA + (m * 16 + fr) * 64 + sw0);
      af[m][1] = *(const bf16x8*)(bA + (m * 16 + fr) * 64 + sw1);
    }
#pragma unroll
    for (int n = 0; n < 4; ++n) {
      bfv[n][0] = *(const bf16x8*)(bB + (wc + n * 16 + fr) * 64 + sw0);
      bfv[n][1] = *(const bf16x8*)(bB + (wc + n * 16 + fr) * 64 + sw1);
    }
#pragma unroll
    for (int m = 0; m < 4; ++m)
#pragma unroll
      for (int n = 0; n < 4; ++n) {
        acc[m][n] = __builtin_amdgcn_mfma_f32_16x16x32_bf16(af[m][0], bfv[n][0], acc[m][n], 0, 0, 0);
        acc[m][n] = __builtin_amdgcn_mfma_f32_16x16x32_bf16(af[m][1], bfv[n][1], acc[m][n], 0, 0, 0);
      }
    __syncthreads();
    cur ^= 1;
  }

#pragma unroll
  for (int m = 0; m < 4; ++m)
#pragma unroll
    for (int n = 0; n < 4; ++n)
#pragma unroll
      for (int r = 0; r < 4; ++r)
        Sf[(m * 16 + q * 4 + r) * 256 + wc + n * 16 + fr] = acc[m][n][r];
  __syncthreads();

#pragma unroll 2
  for (int i = 0; i < 16; ++i) {
    const int row = wid * 16 + i;
    const int gl = rb * 64 + row;
    const f32x4 sv = *(const f32x4*)&Sf[row * 256 + lane * 4];
    const int4 mv = *(const int4*)&mask[((long)b * 256 + gl) * 256 + lane * 4];
    float s[4];
    s[0] = (mv.x == 0) ? 1e-9f : sv[0] * 0.03125f;
    s[1] = (mv.y == 0) ? 1e-9f : sv[1] * 0.03125f;
    s[2] = (mv.z == 0) ? 1e-9f : sv[2] * 0.03125f;
    s[3] = (mv.w == 0) ? 1e-9f : sv[3] * 0.03125f;
    float mx = fmaxf(fmaxf(s[0], s[1]), fmaxf(s[2], s[3]));
#pragma unroll
    for (int off = 32; off; off >>= 1) mx = fmaxf(mx, __shfl_xor(mx, off));
    float e[4], sum = 0.f;
#pragma unroll
    for (int j = 0; j < 4; ++j) {
      e[j] = __expf(s[j] - mx);
      sum += e[j];
    }
#pragma unroll
    for (int off = 32; off; off >>= 1) sum += __shfl_xor(sum, off);
    const float inv = 1.0f / sum;
    ushort4 o;
    o.x = f2bf(e[0] * inv);
    o.y = f2bf(e[1] * inv);
    o.z = f2bf(e[2] * inv);
    o.w = f2bf(e[3] * inv);
    *(ushort4*)&att[((long)bh * 256 + gl) * 256 + lane * 4] = o;
  }
}

// ---------- 128^2 TN GEMM (batched PV), B from vhT2 [bh][lblk][d][l16] ----------
// x[l][d] = att[l][m] * v[m][d]; A = att (rows l, K=m contiguous).
// B chunk (row d, kcols ko..ko+8) lives at lblk=(ko+x8)>>4 sub-block:
//   addr = bh*262144 + ((x8>>4)*16384 + d*16 + (x8&15)) + kt*32768.
__global__ __launch_bounds__(256, 2) void gemm_tn(const ushort_t* __restrict__ Ab,
                                                  const ushort_t* __restrict__ Btp,
                                                  void* __restrict__ Cp, int K, int ldA,
                                                  int ldC, long batchA, long batchB) {
  __shared__ ushort_t smem[16384];
  ushort_t* sA = smem;
  ushort_t* sB = smem + 8192;

  const int bx = blockIdx.x, by = blockIdx.y, z = blockIdx.z;
  const int rowBase = by * 128;
  const int colBase = bx * 128;

  const int t = threadIdx.x;
  const int lane = t & 63;
  const int wid = t >> 6;
  const int wr = (wid >> 1) * 64;
  const int wc = (wid & 1) * 64;
  const int fr = lane & 15;
  const int fk = (lane >> 4) * 8;

  const ushort_t* Atile = Ab + batchA * z + (long)rowBase * ldA;
  const ushort_t* Btile = Btp + batchB * z;

  // B source offsets in vhT2 layout (static part; add kt*32768 per K-tile)
  int sBstat[2];
#pragma unroll
  for (int i = 0; i < 2; ++i) {
    const int c = i * 256 + t;
    const int x8 = (c & 3) * 8;
    sBstat[i] = (x8 >> 4) * 16384 + (colBase + (c >> 2)) * 16 + (x8 & 15);
  }

  f32x4 acc[4][4];
#pragma unroll
  for (int m = 0; m < 4; ++m)
#pragma unroll
    for (int n = 0; n < 4; ++n) acc[m][n] = (f32x4){0.f, 0.f, 0.f, 0.f};

  const int NT = K >> 5;

  auto stageAB = [&](int buf, int kt) {
    const long ko = (long)kt * 32;
#pragma unroll
    for (int i = 0; i < 2; ++i) {
      const int c = i * 256 + t;
      const int cw = i * 256 + (t & 192);
      __builtin_amdgcn_global_load_lds(
          (const AS1 void*)(Atile + (long)(c >> 2) * ldA + ko + (c & 3) * 8),
          (AS3 void*)(sA + buf * 4096 + cw * 8), 16, 0, 0);
      __builtin_amdgcn_global_load_lds(
          (const AS1 void*)(Btile + sBstat[i] + (long)kt * 32768),
          (AS3 void*)(sB + buf * 4096 + cw * 8), 16, 0, 0);
    }
  };

  stageAB(0, 0);
  __syncthreads();

  int cur = 0;
  for (int kt = 0; kt < NT; ++kt) {
    if (kt + 1 < NT) stageAB(cur ^ 1, kt + 1);

    bf16x8 af[4], bfv[4];
    const ushort_t* baseA = sA + cur * 4096 + fk;
    const ushort_t* baseB = sB + cur * 4096 + fk;
#pragma unroll
    for (int m = 0; m < 4; ++m) af[m] = *(const bf16x8*)(baseA + (wr + m * 16 + fr) * 32);
#pragma unroll
    for (int n = 0; n < 4; ++n) bfv[n] = *(const bf16x8*)(baseB + (wc + n * 16 + fr) * 32);

#pragma unroll
    for (int m = 0; m < 4; ++m)
#pragma unroll
      for (int n = 0; n < 4; ++n)
        acc[m][n] = __builtin_amdgcn_mfma_f32_16x16x32_bf16(af[m], bfv[n], acc[m][n], 0, 0, 0);

    __syncthreads();
    cur ^= 1;
  }

  const int rq = (lane >> 4) * 4;
#pragma unroll
  for (int m = 0; m < 4; ++m)
#pragma unroll
    for (int n = 0; n < 4; ++n)
#pragma unroll
      for (int r = 0; r < 4; ++r)
        smem[(wr + m * 16 + rq + r) * 128 + wc + n * 16 + fr] = f2bf(acc[m][n][r]);
  __syncthreads();
  ushort_t* Cb = (ushort_t*)Cp;
  const int c8 = (lane & 15) * 8;
#pragma unroll
  for (int i = 0; i < 8; ++i) {
    const int row = i * 16 + wid * 4 + (lane >> 4);
    const uint4 val = *(const uint4*)(smem + row * 128 + c8);
    const int l = rowBase + row;
    const int orow = ((z >> 4) << 12) + l * 16 + (z & 15); // b*4096 + l*16 + h
    *(uint4*)(Cb + (long)orow * 1024 + colBase + c8) = val;
  }
}

#define SBAR() asm volatile("s_barrier" ::: "memory")
#define LGKM0() asm volatile("s_waitcnt lgkmcnt(0)" ::: "memory")
#define VM(N) asm volatile("s_waitcnt vmcnt(" #N ")" ::: "memory")
#define PH_OPEN() SBAR(); LGKM0(); __builtin_amdgcn_s_setprio(1)
#define PH_CLOSE() __builtin_amdgcn_s_setprio(0); SBAR()

// ---------- 256^2 8-phase TN GEMM, z-batched, early-staged counted-vmcnt ----------
// SMODE 0 = fp32 direct; SMODE 1 = bf16 proj-permute, except z==vzsel which
// stores V transposed into vhT2[bh][lblk][d][l16] (coalesced 32B runs).
template <int SMODE>
__global__ __launch_bounds__(512, 1) void gemm256(const ushort_t* __restrict__ A0,
                                                  const ushort_t* __restrict__ A1,
                                                  const ushort_t* __restrict__ A2,
                                                  const ushort_t* __restrict__ Btp,
                                                  void* __restrict__ Cp, long bStrideZ,
                                                  long cStrideZ, int vzsel) {
  __shared__ ushort_t sm[65536]; // 128 KiB

  const int orig = blockIdx.x;
  const int cpx = (int)gridDim.x >> 3;
  const int wgid = (orig & 7) * cpx + (orig >> 3); // bijective (grid % 8 == 0)
  const int z = wgid >> 8;
  const int tile = wgid & 255;
  const int by = tile >> 2, bx = tile & 3;
  const int rowBase = by * 256, colBase = bx * 256;

  const ushort_t* Ab = (z == 0) ? A0 : (z == 1) ? A1 : A2;
  const ushort_t* Bt = Btp + bStrideZ * z;

  const int t = threadIdx.x;
  const int lane = t & 63;
  const int wid = t >> 6;
  const int wm = wid >> 2; // 0..1
  const int wn = wid & 3;  // 0..3
  const int fr = lane & 15;
  const int q = lane >> 4;

  const int sw0 = ((q ^ (fr & 7)) * 8);
  const int sw1 = (((4 + q) ^ (fr & 7)) * 8);
  const int aoff0 = fr * 64 + sw0;
  const int aoff1 = fr * 64 + sw1;
  const int bbase = ((wn & 1) * 64 + fr) * 64;
  const int boff0 = bbase + sw0;
  const int boff1 = bbase + sw1;

  const ushort_t* srcA[2][2];
  const ushort_t* srcB[2][2];
  int ldsoff[2];
#pragma unroll
  for (int i = 0; i < 2; ++i) {
    const int c = i * 512 + t;
    const int rowc = c >> 3;
    const int gc = (c & 7) ^ (rowc & 7);
    srcA[0][i] = Ab + (long)(rowBase + rowc) * 1024 + gc * 8;
    srcA[1][i] = Ab + (long)(rowBase + 128 + rowc) * 1024 + gc * 8;
    srcB[0][i] = Bt + (long)(colBase + rowc) * 1024 + gc * 8;
    srcB[1][i] = Bt + (long)(colBase + 128 + rowc) * 1024 + gc * 8;
    ldsoff[i] = (c & ~63) * 8;
  }

#define STAGE(kind, h, T)                                                                   \
  do {                                                                                      \
    ushort_t* _d = sm + ((kind) ? 32768 : 0) + ((T) & 1) * 16384 + (h) * 8192;              \
    const ushort_t* _s0 = ((kind) ? srcB[h][0] : srcA[h][0]) + (long)(T) * 64;              \
    __builtin_amdgcn_global_load_lds((const AS1 void*)_s0,                                  \
                                     (AS3 void*)(_d + ldsoff[0]), 16, 0, 0);                \
    const ushort_t* _s1 = ((kind) ? srcB[h][1] : srcA[h][1]) + (long)(T) * 64;              \
    __builtin_amdgcn_global_load_lds((const AS1 void*)_s1,                                  \
                                     (AS3 void*)(_d + ldsoff[1]), 16, 0, 0);                \
  } while (0)

  f32x4 acc[8][4];
#pragma unroll
  for (int m = 0; m < 8; ++m)
#pragma unroll
    for (int n = 0; n < 4; ++n) acc[m][n] = (f32x4){0.f, 0.f, 0.f, 0.f};

  bf16x8 af[4][2], bf0[2][2], bf1[2][2];

#define LDA4(dbuf, msub)                                                         \
  do {                                                                           \
    const ushort_t* _b = sm + (dbuf)*16384 + wm * 8192 + (msub)*4096;            \
    _Pragma("unroll") for (int m2 = 0; m2 < 4; ++m2) {                           \
      af[m2][0] = *(const bf16x8*)(_b + m2 * 1024 + aoff0);                      \
      af[m2][1] = *(const bf16x8*)(_b + m2 * 1024 + aoff1);                      \
    }                                                                            \
  } while (0)

#define LDB2(dbuf, nsub, bfv)                                                    \
  do {                                                                           \
    const ushort_t* _b = sm + 32768 + (dbuf)*16384 + (wn >> 1) * 8192 + (nsub)*2048; \
    _Pragma("unroll") for (int n2 = 0; n2 < 2; ++n2) {                           \
      bfv[n2][0] = *(const bf16x8*)(_b + n2 * 1024 + boff0);                     \
      bfv[n2][1] = *(const bf16x8*)(_b + n2 * 1024 + boff1);                     \
    }                                                                            \
  } while (0)

#define MMQ(msub, nsub, bfv)                                                     \
  do {                                                                           \
    _Pragma("unroll") for (int m2 = 0; m2 < 4; ++m2)                             \
        _Pragma("unroll") for (int n2 = 0; n2 < 2; ++n2) {                       \
      acc[(msub)*4 + m2][(nsub)*2 + n2] = __builtin_amdgcn_mfma_f32_16x16x32_bf16( \
          af[m2][0], bfv[n2][0], acc[(msub)*4 + m2][(nsub)*2 + n2], 0, 0, 0);    \
      acc[(msub)*4 + m2][(nsub)*2 + n2] = __builtin_amdgcn_mfma_f32_16x16x32_bf16( \
          af[m2][1], bfv[n2][1], acc[(msub)*4 + m2][(nsub)*2 + n2], 0, 0, 0);    \
    }                                                                            \
  } while (0)

  const int NT = 16; // K=1024, K-tiles of 64
  const int NI = 8;

  // prologue: tiles 0 and 1 fully staged; VM(8) drains ALL of tile0
  STAGE(0, 0, 0);
  STAGE(0, 1, 0);
  STAGE(1, 0, 0);
  STAGE(1, 1, 0);
  STAGE(0, 0, 1);
  STAGE(0, 1, 1);
  STAGE(1, 0, 1);
  STAGE(1, 1, 1);
  VM(8);
  SBAR();

  for (int it = 0; it < NI - 1; ++it) {
    const int T0 = 2 * it;
    LDA4(0, 0);
    LDB2(0, 0, bf0);
    PH_OPEN(); MMQ(0, 0, bf0); PH_CLOSE();
    LDB2(0, 1, bf1);
    PH_OPEN(); MMQ(0, 1, bf1); PH_CLOSE();
    LDA4(0, 1);
    STAGE(1, 0, T0 + 2);
    STAGE(1, 1, T0 + 2);
    PH_OPEN(); MMQ(1, 1, bf1); PH_CLOSE();
    STAGE(0, 0, T0 + 2);
    STAGE(0, 1, T0 + 2);
    SBAR();
    __builtin_amdgcn_s_setprio(1);
    MMQ(1, 0, bf0);
    __builtin_amdgcn_s_setprio(0);
    VM(8); // drains tile T0+1 (>=4 phases cover); leaves T0+2
    SBAR();
    LDA4(1, 0);
    LDB2(1, 0, bf0);
    PH_OPEN(); MMQ(0, 0, bf0); PH_CLOSE();
    LDB2(1, 1, bf1);
    PH_OPEN(); MMQ(0, 1, bf1); PH_CLOSE();
    LDA4(1, 1);
    STAGE(1, 0, T0 + 3);
    STAGE(1, 1, T0 + 3);
    PH_OPEN(); MMQ(1, 1, bf1); PH_CLOSE();
    STAGE(0, 0, T0 + 3);
    STAGE(0, 1, T0 + 3);
    SBAR();
    __builtin_amdgcn_s_setprio(1);
    MMQ(1, 0, bf0);
    __builtin_amdgcn_s_setprio(0);
    VM(8); // drains tile T0+2; leaves T0+3
    SBAR();
  }

  { // peeled last iteration (tiles 14,15): no new stages
    LDA4(0, 0);
    LDB2(0, 0, bf0);
    PH_OPEN(); MMQ(0, 0, bf0); PH_CLOSE();
    LDB2(0, 1, bf1);
    PH_OPEN(); MMQ(0, 1, bf1); PH_CLOSE();
    LDA4(0, 1);
    PH_OPEN(); MMQ(1, 1, bf1); PH_CLOSE();
    SBAR();
    __builtin_amdgcn_s_setprio(1);
    MMQ(1, 0, bf0);
    __builtin_amdgcn_s_setprio(0);
    VM(0); // drains tile15 (>=4 phases cover)
    SBAR();
    LDA4(1, 0);
    LDB2(1, 0, bf0);
    PH_OPEN(); MMQ(0, 0, bf0); PH_CLOSE();
    LDB2(1, 1, bf1);
    PH_OPEN(); MMQ(0, 1, bf1); PH_CLOSE();
    LDA4(1, 1);
    PH_OPEN(); MMQ(1, 1, bf1); PH_CLOSE();
    SBAR();
    MMQ(1, 0, bf0);
    SBAR();
  }

  const int rq = q * 4;
  if constexpr (SMODE == 0) {
    float* Cf = (float*)Cp + cStrideZ * z;
#pragma unroll
    for (int m = 0; m < 8; ++m)
#pragma unroll
      for (int n = 0; n < 4; ++n)
#pragma unroll
        for (int r = 0; r < 4; ++r) {
          const int row = rowBase + wm * 128 + m * 16 + rq + r;
          const int col = colBase + wn * 64 + n * 16 + fr;
          Cf[(long)row * 1024 + col] = acc[m][n][r];
        }
  } else {
    // swizzled C-tile in LDS (shared by both permute variants)
#pragma unroll
    for (int m = 0; m < 8; ++m)
#pragma unroll
      for (int n = 0; n < 4; ++n)
#pragma unroll
        for (int r = 0; r < 4; ++r) {
          const int row = wm * 128 + m * 16 + rq + r;
          const int col = wn * 64 + n * 16 + fr;
          sm[row * 256 + (((col >> 3) ^ (row & 7)) * 8) + (col & 7)] = f2bf(acc[m][n][r]);
        }
    __syncthreads();
    ushort_t* Cb = (ushort_t*)Cp + cStrideZ * z;
    if (z != vzsel) {
      // proj-permute: row grow = b*4096 + s, s = l*16+h -> (b*16+h)*256 + l
      const int cc = t & 31;
      const int r0 = t >> 5;
#pragma unroll
      for (int i = 0; i < 16; ++i) {
        const int row = r0 + i * 16;
        const uint4 val = *(const uint4*)(sm + row * 256 + ((cc ^ (row & 7)) * 8));
        const int grow = rowBase + row;
        const int b = grow >> 12;
        const int s = grow & 4095;
        const int orow = ((b << 4) + (s & 15)) * 256 + (s >> 4);
        *(uint4*)(Cb + (long)orow * 1024 + colBase + cc * 8) = val;
      }
    } else {
      // V transposed store: vhT2[bh][lblk][d][l16]; tile covers one lblk.
      const int bq = rowBase >> 12;
      const int lblk = (rowBase & 4095) >> 8;
      ushort_t* base0 = Cb + (long)lblk * 16384;
#pragma unroll
      for (int i = 0; i < 8; ++i) {
        const int cid = i * 512 + t; // d fast, h slow -> coalesced stores
        const int d = cid & 255;
        const int h = cid >> 8;
        uint_t w[8];
#pragma unroll
        for (int j = 0; j < 8; ++j) {
          const int r0 = (2 * j) * 16 + h;
          const int r1 = (2 * j + 1) * 16 + h;
          const ushort_t v0 = sm[r0 * 256 + (((d >> 3) ^ (r0 & 7)) * 8) + (d & 7)];
          const ushort_t v1 = sm[r1 * 256 + (((d >> 3) ^ (r1 & 7)) * 8) + (d & 7)];
          w[j] = (uint_t)v0 | ((uint_t)v1 << 16);
        }
        ushort_t* dst = base0 + (long)(bq * 16 + h) * 262144 + (colBase + d) * 16;
        *(uint4*)dst = make_uint4(w[0], w[1], w[2], w[3]);
        *(uint4*)(dst + 8) = make_uint4(w[4], w[5], w[6], w[7]);
      }
    }
  }
#undef STAGE
#undef LDA4
#undef LDB2
#undef MMQ
}

extern "C" void kernel_launch(void* const* d_in, const int* in_sizes, int n_in,
                              void* d_out, int out_size, void* d_ws, size_t ws_size,
                              hipStream_t stream) {
  const float* q = (const float*)d_in[0];
  const float* k = (const float*)d_in[1];
  const float* v = (const float*)d_in[2];
  const int* mask = (const int*)d_in[3];
  const float* Wq = (const float*)d_in[4];
  const float* Wk = (const float*)d_in[5];
  const float* Wv = (const float*)d_in[6];
  const float* Wo = (const float*)d_in[7];
  float* out = (float*)d_out;

  char* ws = (char*)d_ws;
  const size_t MB = 1024 * 1024;
  ushort_t* WT = (ushort_t*)ws; // packed [4][1024][1024] bf16: Wq,Wk,Wv,Wo (8MB)
  const dim3 tb(32, 8);
  transpose_w4<<<dim3(32, 32, 4), tb, 0, stream>>>(Wq, Wk, Wv, Wo, WT);

  const bool big = ws_size >= (size_t)200 * MB;

  if (big) {
    // layout: WT 0..8 | qkvb 8..104 | qh 104..136 | kh 136..168 | vhT2 168..200
    // after proj (qkvb dead): att 40..48 | x 48..80
    ushort_t* qkvb = (ushort_t*)(ws + 8 * MB);
    ushort_t* qh = (ushort_t*)(ws + 104 * MB);
    ushort_t* kh = (ushort_t*)(ws + 136 * MB);
    ushort_t* vhT2 = (ushort_t*)(ws + 168 * MB);
    ushort_t* att = (ushort_t*)(ws + 40 * MB);
    ushort_t* x = (ushort_t*)(ws + 48 * MB);

    cvt3<<<dim3(8192, 3), 256, 0, stream>>>((const float4*)q, (const float4*)k,
                                            (const float4*)v, (uint4*)qkvb);
    // one batched dispatch: z=0/1 -> qh/kh proj-permute; z=2 -> vhT2 transposed
    gemm256<1><<<768, 512, 0, stream>>>(qkvb, qkvb + (size_t)16777216,
                                        qkvb + (size_t)33554432, WT, qh, 1 << 20,
                                        (long)16777216, 2);
    score_sm<<<256, 256, 0, stream>>>(qh, kh, mask, att);
    gemm_tn<<<dim3(8, 2, BHN), 256, 0, stream>>>(att, vhT2, x, 256, 256, 1024,
                                                 (long)65536, (long)262144);
    gemm256<0><<<256, 512, 0, stream>>>(x, x, x, WT + (size_t)3145728, out, 0, 0, -1);
  } else {
    // serial fallback (peak 168MB): WT 0..8 | qb 8..40 | qh 40..72 | kh 72..104
    // | vhT2 104..136 ; after proj: att 8..16 | x 16..48
    ushort_t* qb = (ushort_t*)(ws + 8 * MB);
    ushort_t* qh = (ushort_t*)(ws + 40 * MB);
    ushort_t* kh = (ushort_t*)(ws + 72 * MB);
    ushort_t* vhT2 = (ushort_t*)(ws + 104 * MB);
    ushort_t* att = (ushort_t*)(ws + 8 * MB);
    ushort_t* x = (ushort_t*)(ws + 16 * MB);

    cvt3<<<dim3(8192, 1), 256, 0, stream>>>((const float4*)q, (const float4*)q,
                                            (const float4*)q, (uint4*)qb);
    gemm256<1><<<256, 512, 0, stream>>>(qb, qb, qb, WT, qh, 0, 0, -1);
    cvt3<<<dim3(8192, 1), 256, 0, stream>>>((const float4*)k, (const float4*)k,
                                            (const float4*)k, (uint4*)qb);
    gemm256<1><<<256, 512, 0, stream>>>(qb, qb, qb, WT + (size_t)1048576, kh, 0, 0, -1);
    cvt3<<<dim3(8192, 1), 256, 0, stream>>>((const float4*)v, (const float4*)v,
                                            (const float4*)v, (uint4*)qb);
    gemm256<1><<<256, 512, 0, stream>>>(qb, qb, qb, WT + (size_t)2097152, vhT2, 0, 0, 0);
    score_sm<<<256, 256, 0, stream>>>(qh, kh, mask, att);
    gemm_tn<<<dim3(8, 2, BHN), 256, 0, stream>>>(att, vhT2, x, 256, 256, 1024,
                                                 (long)65536, (long)262144);
    gemm256<0><<<256, 512, 0, stream>>>(x, x, x, WT + (size_t)3145728, out, 0, 0, -1);
  }
}

// Round 12
// 256.671 us; speedup vs baseline: 1.3025x; 1.0047x over previous
//
#include <hip/hip_runtime.h>
#include <hip/hip_bf16.h>

typedef __bf16 bf16x8 __attribute__((ext_vector_type(8)));
typedef float f32x4 __attribute__((ext_vector_type(4)));
typedef unsigned short ushort_t;
typedef unsigned int uint_t;

#define HN 16
#define LSEQ 256
#define DD 1024
#define BB 4
#define SS 4096
#define MROWS (BB * SS) /* 16384 */
#define BHN (BB * HN)   /* 64 */

#define AS1 __attribute__((address_space(1)))
#define AS3 __attribute__((address_space(3)))

__device__ __forceinline__ ushort_t f2bf(float f) {
  uint_t u = __builtin_bit_cast(uint_t, f);
  u += 0x7fffu + ((u >> 16) & 1u); // RNE
  return (ushort_t)(u >> 16);
}
__device__ __forceinline__ uint_t pk2(float lo, float hi) {
  return (uint_t)f2bf(lo) | ((uint_t)f2bf(hi) << 16);
}

// ---------- prep: fp32->bf16 convert for q,k,v  +  packed weight transpose ----------
// blocks [0, 24576): cvt (z = bid/8192); blocks [24576, 28672): transpose W0..W3.
__global__ __launch_bounds__(256) void prep(const float* __restrict__ q,
                                            const float* __restrict__ k,
                                            const float* __restrict__ v,
                                            const float* __restrict__ W0,
                                            const float* __restrict__ W1,
                                            const float* __restrict__ W2,
                                            const float* __restrict__ W3,
                                            uint4* __restrict__ qkvb,
                                            ushort_t* __restrict__ WT) {
  const int bid = blockIdx.x;
  const int t = threadIdx.x;
  if (bid < 24576) {
    const int z = bid >> 13;
    const float4* in = (const float4*)((z == 0) ? q : (z == 1) ? k : v);
    const long i = (long)(bid & 8191) * 256 + t;
    const float4 a = in[i * 2];
    const float4 b = in[i * 2 + 1];
    uint4 o;
    o.x = pk2(a.x, a.y);
    o.y = pk2(a.z, a.w);
    o.z = pk2(b.x, b.y);
    o.w = pk2(b.z, b.w);
    qkvb[(long)z * 2097152 + i] = o;
  } else {
    __shared__ float tile[32][33];
    const int b2 = bid - 24576;
    const int z = b2 >> 10;
    const float* W = (z == 0) ? W0 : (z == 1) ? W1 : (z == 2) ? W2 : W3;
    ushort_t* dst = WT + (long)z * 1048576;
    const int rem = b2 & 1023;
    const int bn = (rem & 31) * 32, bk = (rem >> 5) * 32;
    const int tx = t & 31, ty = t >> 5;
#pragma unroll
    for (int j = 0; j < 32; j += 8)
      tile[ty + j][tx] = W[(long)(bk + ty + j) * DD + bn + tx];
    __syncthreads();
#pragma unroll
    for (int j = 0; j < 32; j += 8)
      dst[(long)(bn + ty + j) * DD + bk + tx] = f2bf(tile[tx][ty + j]);
  }
}

// ---------- fused attention: scores + mask + softmax + PV ----------
// per block: one (b,h), 64 q-rows. Reads qh,kh (proj-permuted) and vhT2
// [bh][lblk][d][l16]; writes x[b*4096+l*16+h][d] bf16. LDS 112 KB, 1 block/CU.
__global__ __launch_bounds__(256, 1) void attn_fused(const ushort_t* __restrict__ qh,
                                                     const ushort_t* __restrict__ kh,
                                                     const ushort_t* __restrict__ vhT2,
                                                     const int* __restrict__ mask,
                                                     ushort_t* __restrict__ x) {
  __shared__ char smemraw[114688];
  ushort_t* sA = (ushort_t*)smemraw;            // score A staging: 2 x 4096 elems
  ushort_t* sB = (ushort_t*)(smemraw + 16384);  // score B staging: 2 x 16384 elems
  float* Sf = (float*)smemraw;                  // [64][256] fp32 (aliases staging)
  ushort_t* sPV = (ushort_t*)smemraw;           // PV B dbuf: 2 x 16384 elems (aliases)
  ushort_t* sC = (ushort_t*)(smemraw + 32768);  // PV C-stage [64][256] (aliases buf1)
  ushort_t* attL = (ushort_t*)(smemraw + 81920); // att [64][256] bf16, chunk-XOR swz

  const int orig = blockIdx.x;
  const int wgid = (orig & 7) * 32 + (orig >> 3); // XCD-chunked, 256 % 8 == 0
  const int bh = wgid >> 2, rb = wgid & 3;
  const int b = bh >> 4;
  const ushort_t* A = qh + ((long)bh * 256 + rb * 64) * 1024;
  const ushort_t* Bk = kh + (long)bh * 256 * 1024;
  const ushort_t* Vb = vhT2 + (long)bh * 262144;

  const int t = threadIdx.x, lane = t & 63, wid = t >> 6;
  const int fr = lane & 15, q = lane >> 4;
  const int wc = wid * 64;
  const int sw0 = (q ^ (fr & 7)) * 8;
  const int sw1 = ((4 + q) ^ (fr & 7)) * 8;

  int srcAo[2], dstA[2], srcBo[8], dstB[8];
#pragma unroll
  for (int i = 0; i < 2; ++i) {
    const int c = i * 256 + t, row = c >> 3, gc = (c & 7) ^ (row & 7);
    srcAo[i] = row * 1024 + gc * 8;
    dstA[i] = (i * 256 + (t & 192)) * 8;
  }
#pragma unroll
  for (int i = 0; i < 8; ++i) {
    const int c = i * 256 + t, row = c >> 3, gc = (c & 7) ^ (row & 7);
    srcBo[i] = row * 1024 + gc * 8;
    dstB[i] = (i * 256 + (t & 192)) * 8;
  }
  // PV B staging precompute: chunk c = i*256+t; dr = c>>3; gc = (c&7)^(dr&7)
  int pvOff[8], pvDst[8];
#pragma unroll
  for (int i = 0; i < 8; ++i) {
    const int c = i * 256 + t, dr = c >> 3, gc = (c & 7) ^ (dr & 7);
    pvOff[i] = (gc >> 1) * 16384 + dr * 16 + (gc & 1) * 8;
    pvDst[i] = (i * 256 + (t & 192)) * 8;
  }

  auto stage = [&](int buf, int kt) {
    const int ko = kt * 64;
#pragma unroll
    for (int i = 0; i < 2; ++i)
      __builtin_amdgcn_global_load_lds(
          (const AS1 void*)(A + srcAo[i] + ko),
          (AS3 void*)(sA + buf * 4096 + dstA[i]), 16, 0, 0);
#pragma unroll
    for (int i = 0; i < 8; ++i)
      __builtin_amdgcn_global_load_lds(
          (const AS1 void*)(Bk + srcBo[i] + ko),
          (AS3 void*)(sB + buf * 16384 + dstB[i]), 16, 0, 0);
  };

  f32x4 acc[4][4];
#pragma unroll
  for (int m = 0; m < 4; ++m)
#pragma unroll
    for (int n = 0; n < 4; ++n) acc[m][n] = (f32x4){0.f, 0.f, 0.f, 0.f};

  // ---- scores: S = qh_tile @ kh^T, K=1024 ----
  stage(0, 0);
  __syncthreads();
  int cur = 0;
  for (int kt = 0; kt < 16; ++kt) {
    if (kt < 15) stage(cur ^ 1, kt + 1);
    bf16x8 af[4][2], bfv[4][2];
    const ushort_t* bA = sA + cur * 4096;
    const ushort_t* bB = sB + cur * 16384;
#pragma unroll
    for (int m = 0; m < 4; ++m) {
      af[m][0] = *(const bf16x8*)(bA + (m * 16 + fr) * 64 + sw0);
      af[m][1] = *(const bf16x8*)(bA + (m * 16 + fr) * 64 + sw1);
    }
#pragma unroll
    for (int n = 0; n < 4; ++n) {
      bfv[n][0] = *(const bf16x8*)(bB + (wc + n * 16 + fr) * 64 + sw0);
      bfv[n][1] = *(const bf16x8*)(bB + (wc + n * 16 + fr) * 64 + sw1);
    }
#pragma unroll
    for (int m = 0; m < 4; ++m)
#pragma unroll
      for (int n = 0; n < 4; ++n) {
        acc[m][n] = __builtin_amdgcn_mfma_f32_16x16x32_bf16(af[m][0], bfv[n][0], acc[m][n], 0, 0, 0);
        acc[m][n] = __builtin_amdgcn_mfma_f32_16x16x32_bf16(af[m][1], bfv[n][1], acc[m][n], 0, 0, 0);
      }
    __syncthreads();
    cur ^= 1;
  }

  // raw S -> LDS fp32
#pragma unroll
  for (int m = 0; m < 4; ++m)
#pragma unroll
    for (int n = 0; n < 4; ++n)
#pragma unroll
      for (int r = 0; r < 4; ++r)
        Sf[(m * 16 + q * 4 + r) * 256 + wc + n * 16 + fr] = acc[m][n][r];
  __syncthreads();

  // ---- softmax (wave-per-row), att -> LDS bf16 (chunk-XOR swizzled) ----
#pragma unroll 2
  for (int i = 0; i < 16; ++i) {
    const int row = wid * 16 + i;
    const int gl = rb * 64 + row;
    const f32x4 sv = *(const f32x4*)&Sf[row * 256 + lane * 4];
    const int4 mv = *(const int4*)&mask[((long)b * 256 + gl) * 256 + lane * 4];
    float s[4];
    s[0] = (mv.x == 0) ? 1e-9f : sv[0] * 0.03125f;
    s[1] = (mv.y == 0) ? 1e-9f : sv[1] * 0.03125f;
    s[2] = (mv.z == 0) ? 1e-9f : sv[2] * 0.03125f;
    s[3] = (mv.w == 0) ? 1e-9f : sv[3] * 0.03125f;
    float mx = fmaxf(fmaxf(s[0], s[1]), fmaxf(s[2], s[3]));
#pragma unroll
    for (int off = 32; off; off >>= 1) mx = fmaxf(mx, __shfl_xor(mx, off));
    float e[4], sum = 0.f;
#pragma unroll
    for (int j = 0; j < 4; ++j) {
      e[j] = __expf(s[j] - mx);
      sum += e[j];
    }
#pragma unroll
    for (int off = 32; off; off >>= 1) sum += __shfl_xor(sum, off);
    const float inv = 1.0f / sum;
    ushort4 o;
    o.x = f2bf(e[0] * inv);
    o.y = f2bf(e[1] * inv);
    o.z = f2bf(e[2] * inv);
    o.w = f2bf(e[3] * inv);
    const int mch = lane >> 1; // 16B chunk (4 elems at lane*4 -> chunk lane/2)
    *(ushort4*)(attL + row * 256 + (((mch ^ (row & 7)) << 3) + (lane & 1) * 4)) = o;
  }
  __syncthreads(); // att complete; Sf/staging dead -> PV may reuse [0,64K)

  // ---- PV: x[64][1024] = att @ vh, in 4 d-blocks of 256, K=256 in 4 tiles ----
  const int r0 = t >> 2, qd = t & 3;
  const long orow = (long)((b << 12) + (rb * 64 + r0) * 16 + (bh & 15));
  for (int nb = 0; nb < 4; ++nb) {
#pragma unroll
    for (int m = 0; m < 4; ++m)
#pragma unroll
      for (int n = 0; n < 4; ++n) acc[m][n] = (f32x4){0.f, 0.f, 0.f, 0.f};

    // stage B tile0 (256d x 64m) into buf0
#pragma unroll
    for (int i = 0; i < 8; ++i)
      __builtin_amdgcn_global_load_lds(
          (const AS1 void*)(Vb + pvOff[i] + nb * 4096),
          (AS3 void*)(sPV + pvDst[i]), 16, 0, 0);
    __syncthreads();

    int pbuf = 0;
    for (int mt = 0; mt < 4; ++mt) {
      if (mt < 3) {
#pragma unroll
        for (int i = 0; i < 8; ++i)
          __builtin_amdgcn_global_load_lds(
              (const AS1 void*)(Vb + pvOff[i] + (mt + 1) * 65536 + nb * 4096),
              (AS3 void*)(sPV + (pbuf ^ 1) * 16384 + pvDst[i]), 16, 0, 0);
      }
#pragma unroll
      for (int kk = 0; kk < 2; ++kk) {
        bf16x8 af[4], bfv[4];
#pragma unroll
        for (int m = 0; m < 4; ++m) {
          const int l = m * 16 + fr;
          af[m] = *(const bf16x8*)(attL + l * 256 + (((mt * 8 + kk * 4 + q) ^ (l & 7)) << 3));
        }
#pragma unroll
        for (int n = 0; n < 4; ++n) {
          const int dr = wc + n * 16 + fr;
          bfv[n] = *(const bf16x8*)(sPV + pbuf * 16384 + dr * 64 + (((kk * 4 + q) ^ (dr & 7)) << 3));
        }
#pragma unroll
        for (int m = 0; m < 4; ++m)
#pragma unroll
          for (int n = 0; n < 4; ++n)
            acc[m][n] = __builtin_amdgcn_mfma_f32_16x16x32_bf16(af[m], bfv[n], acc[m][n], 0, 0, 0);
      }
      __syncthreads();
      pbuf ^= 1;
    }

    // C-tile -> LDS (buf1 region, dead) with chunk-XOR; then coalesced permuted store
#pragma unroll
    for (int m = 0; m < 4; ++m)
#pragma unroll
      for (int n = 0; n < 4; ++n)
#pragma unroll
        for (int r = 0; r < 4; ++r) {
          const int row = m * 16 + q * 4 + r;
          const int col = wc + n * 16 + fr;
          sC[row * 256 + (((col >> 3) ^ (row & 7)) << 3) + (col & 7)] = f2bf(acc[m][n][r]);
        }
    __syncthreads();
    ushort_t* dst = x + orow * 1024 + nb * 256 + qd * 64;
#pragma unroll
    for (int j = 0; j < 8; ++j) {
      const int cc = qd * 8 + j;
      *(uint4*)(dst + j * 8) = *(const uint4*)(sC + r0 * 256 + ((cc ^ (r0 & 7)) << 3));
    }
    __syncthreads(); // C-read done before next nb overwrites bufs
  }
}

#define SBAR() asm volatile("s_barrier" ::: "memory")
#define LGKM0() asm volatile("s_waitcnt lgkmcnt(0)" ::: "memory")
#define VM(N) asm volatile("s_waitcnt vmcnt(" #N ")" ::: "memory")
#define PH_OPEN() SBAR(); LGKM0(); __builtin_amdgcn_s_setprio(1)
#define PH_CLOSE() __builtin_amdgcn_s_setprio(0); SBAR()

// ---------- 256^2 8-phase TN GEMM, z-batched, early-staged counted-vmcnt ----------
// SMODE 0 = fp32 direct; SMODE 1 = bf16 proj-permute, except z==vzsel which
// stores V transposed into vhT2[bh][lblk][d][l16] (coalesced 32B runs).
template <int SMODE>
__global__ __launch_bounds__(512, 1) void gemm256(const ushort_t* __restrict__ A0,
                                                  const ushort_t* __restrict__ A1,
                                                  const ushort_t* __restrict__ A2,
                                                  const ushort_t* __restrict__ Btp,
                                                  void* __restrict__ Cp, long bStrideZ,
                                                  long cStrideZ, int vzsel) {
  __shared__ ushort_t sm[65536]; // 128 KiB

  const int orig = blockIdx.x;
  const int cpx = (int)gridDim.x >> 3;
  const int wgid = (orig & 7) * cpx + (orig >> 3); // bijective (grid % 8 == 0)
  const int z = wgid >> 8;
  const int tile = wgid & 255;
  const int by = tile >> 2, bx = tile & 3;
  const int rowBase = by * 256, colBase = bx * 256;

  const ushort_t* Ab = (z == 0) ? A0 : (z == 1) ? A1 : A2;
  const ushort_t* Bt = Btp + bStrideZ * z;

  const int t = threadIdx.x;
  const int lane = t & 63;
  const int wid = t >> 6;
  const int wm = wid >> 2; // 0..1
  const int wn = wid & 3;  // 0..3
  const int fr = lane & 15;
  const int q = lane >> 4;

  const int sw0 = ((q ^ (fr & 7)) * 8);
  const int sw1 = (((4 + q) ^ (fr & 7)) * 8);
  const int aoff0 = fr * 64 + sw0;
  const int aoff1 = fr * 64 + sw1;
  const int bbase = ((wn & 1) * 64 + fr) * 64;
  const int boff0 = bbase + sw0;
  const int boff1 = bbase + sw1;

  const ushort_t* srcA[2][2];
  const ushort_t* srcB[2][2];
  int ldsoff[2];
#pragma unroll
  for (int i = 0; i < 2; ++i) {
    const int c = i * 512 + t;
    const int rowc = c >> 3;
    const int gc = (c & 7) ^ (rowc & 7);
    srcA[0][i] = Ab + (long)(rowBase + rowc) * 1024 + gc * 8;
    srcA[1][i] = Ab + (long)(rowBase + 128 + rowc) * 1024 + gc * 8;
    srcB[0][i] = Bt + (long)(colBase + rowc) * 1024 + gc * 8;
    srcB[1][i] = Bt + (long)(colBase + 128 + rowc) * 1024 + gc * 8;
    ldsoff[i] = (c & ~63) * 8;
  }

#define STAGE(kind, h, T)                                                                   \
  do {                                                                                      \
    ushort_t* _d = sm + ((kind) ? 32768 : 0) + ((T) & 1) * 16384 + (h) * 8192;              \
    const ushort_t* _s0 = ((kind) ? srcB[h][0] : srcA[h][0]) + (long)(T) * 64;              \
    __builtin_amdgcn_global_load_lds((const AS1 void*)_s0,                                  \
                                     (AS3 void*)(_d + ldsoff[0]), 16, 0, 0);                \
    const ushort_t* _s1 = ((kind) ? srcB[h][1] : srcA[h][1]) + (long)(T) * 64;              \
    __builtin_amdgcn_global_load_lds((const AS1 void*)_s1,                                  \
                                     (AS3 void*)(_d + ldsoff[1]), 16, 0, 0);                \
  } while (0)

  f32x4 acc[8][4];
#pragma unroll
  for (int m = 0; m < 8; ++m)
#pragma unroll
    for (int n = 0; n < 4; ++n) acc[m][n] = (f32x4){0.f, 0.f, 0.f, 0.f};

  bf16x8 af[4][2], bf0[2][2], bf1[2][2];

#define LDA4(dbuf, msub)                                                         \
  do {                                                                           \
    const ushort_t* _b = sm + (dbuf)*16384 + wm * 8192 + (msub)*4096;            \
    _Pragma("unroll") for (int m2 = 0; m2 < 4; ++m2) {                           \
      af[m2][0] = *(const bf16x8*)(_b + m2 * 1024 + aoff0);                      \
      af[m2][1] = *(const bf16x8*)(_b + m2 * 1024 + aoff1);                      \
    }                                                                            \
  } while (0)

#define LDB2(dbuf, nsub, bfv)                                                    \
  do {                                                                           \
    const ushort_t* _b = sm + 32768 + (dbuf)*16384 + (wn >> 1) * 8192 + (nsub)*2048; \
    _Pragma("unroll") for (int n2 = 0; n2 < 2; ++n2) {                           \
      bfv[n2][0] = *(const bf16x8*)(_b + n2 * 1024 + boff0);                     \
      bfv[n2][1] = *(const bf16x8*)(_b + n2 * 1024 + boff1);                     \
    }                                                                            \
  } while (0)

#define MMQ(msub, nsub, bfv)                                                     \
  do {                                                                           \
    _Pragma("unroll") for (int m2 = 0; m2 < 4; ++m2)                             \
        _Pragma("unroll") for (int n2 = 0; n2 < 2; ++n2) {                       \
      acc[(msub)*4 + m2][(nsub)*2 + n2] = __builtin_amdgcn_mfma_f32_16x16x32_bf16( \
          af[m2][0], bfv[n2][0], acc[(msub)*4 + m2][(nsub)*2 + n2], 0, 0, 0);    \
      acc[(msub)*4 + m2][(nsub)*2 + n2] = __builtin_amdgcn_mfma_f32_16x16x32_bf16( \
          af[m2][1], bfv[n2][1], acc[(msub)*4 + m2][(nsub)*2 + n2], 0, 0, 0);    \
    }                                                                            \
  } while (0)

  const int NT = 16; // K=1024, K-tiles of 64
  const int NI = 8;

  // prologue: tiles 0 and 1 fully staged; VM(8) drains ALL of tile0
  STAGE(0, 0, 0);
  STAGE(0, 1, 0);
  STAGE(1, 0, 0);
  STAGE(1, 1, 0);
  STAGE(0, 0, 1);
  STAGE(0, 1, 1);
  STAGE(1, 0, 1);
  STAGE(1, 1, 1);
  VM(8);
  SBAR();

  for (int it = 0; it < NI - 1; ++it) {
    const int T0 = 2 * it;
    LDA4(0, 0);
    LDB2(0, 0, bf0);
    PH_OPEN(); MMQ(0, 0, bf0); PH_CLOSE();
    LDB2(0, 1, bf1);
    PH_OPEN(); MMQ(0, 1, bf1); PH_CLOSE();
    LDA4(0, 1);
    STAGE(1, 0, T0 + 2);
    STAGE(1, 1, T0 + 2);
    PH_OPEN(); MMQ(1, 1, bf1); PH_CLOSE();
    STAGE(0, 0, T0 + 2);
    STAGE(0, 1, T0 + 2);
    SBAR();
    __builtin_amdgcn_s_setprio(1);
    MMQ(1, 0, bf0);
    __builtin_amdgcn_s_setprio(0);
    VM(8); // drains tile T0+1 (>=4 phases cover); leaves T0+2
    SBAR();
    LDA4(1, 0);
    LDB2(1, 0, bf0);
    PH_OPEN(); MMQ(0, 0, bf0); PH_CLOSE();
    LDB2(1, 1, bf1);
    PH_OPEN(); MMQ(0, 1, bf1); PH_CLOSE();
    LDA4(1, 1);
    STAGE(1, 0, T0 + 3);
    STAGE(1, 1, T0 + 3);
    PH_OPEN(); MMQ(1, 1, bf1); PH_CLOSE();
    STAGE(0, 0, T0 + 3);
    STAGE(0, 1, T0 + 3);
    SBAR();
    __builtin_amdgcn_s_setprio(1);
    MMQ(1, 0, bf0);
    __builtin_amdgcn_s_setprio(0);
    VM(8); // drains tile T0+2; leaves T0+3
    SBAR();
  }

  { // peeled last iteration (tiles 14,15): no new stages
    LDA4(0, 0);
    LDB2(0, 0, bf0);
    PH_OPEN(); MMQ(0, 0, bf0); PH_CLOSE();
    LDB2(0, 1, bf1);
    PH_OPEN(); MMQ(0, 1, bf1); PH_CLOSE();
    LDA4(0, 1);
    PH_OPEN(); MMQ(1, 1, bf1); PH_CLOSE();
    SBAR();
    __builtin_amdgcn_s_setprio(1);
    MMQ(1, 0, bf0);
    __builtin_amdgcn_s_setprio(0);
    VM(0); // drains tile15 (>=4 phases cover)
    SBAR();
    LDA4(1, 0);
    LDB2(1, 0, bf0);
    PH_OPEN(); MMQ(0, 0, bf0); PH_CLOSE();
    LDB2(1, 1, bf1);
    PH_OPEN(); MMQ(0, 1, bf1); PH_CLOSE();
    LDA4(1, 1);
    PH_OPEN(); MMQ(1, 1, bf1); PH_CLOSE();
    SBAR();
    MMQ(1, 0, bf0);
    SBAR();
  }

  const int rq = q * 4;
  if constexpr (SMODE == 0) {
    float* Cf = (float*)Cp + cStrideZ * z;
#pragma unroll
    for (int m = 0; m < 8; ++m)
#pragma unroll
      for (int n = 0; n < 4; ++n)
#pragma unroll
        for (int r = 0; r < 4; ++r) {
          const int row = rowBase + wm * 128 + m * 16 + rq + r;
          const int col = colBase + wn * 64 + n * 16 + fr;
          Cf[(long)row * 1024 + col] = acc[m][n][r];
        }
  } else {
    // swizzled C-tile in LDS (shared by both permute variants)
#pragma unroll
    for (int m = 0; m < 8; ++m)
#pragma unroll
      for (int n = 0; n < 4; ++n)
#pragma unroll
        for (int r = 0; r < 4; ++r) {
          const int row = wm * 128 + m * 16 + rq + r;
          const int col = wn * 64 + n * 16 + fr;
          sm[row * 256 + (((col >> 3) ^ (row & 7)) * 8) + (col & 7)] = f2bf(acc[m][n][r]);
        }
    __syncthreads();
    ushort_t* Cb = (ushort_t*)Cp + cStrideZ * z;
    if (z != vzsel) {
      // proj-permute: row grow = b*4096 + s, s = l*16+h -> (b*16+h)*256 + l
      const int cc = t & 31;
      const int r0 = t >> 5;
#pragma unroll
      for (int i = 0; i < 16; ++i) {
        const int row = r0 + i * 16;
        const uint4 val = *(const uint4*)(sm + row * 256 + ((cc ^ (row & 7)) * 8));
        const int grow = rowBase + row;
        const int b = grow >> 12;
        const int s = grow & 4095;
        const int orow = ((b << 4) + (s & 15)) * 256 + (s >> 4);
        *(uint4*)(Cb + (long)orow * 1024 + colBase + cc * 8) = val;
      }
    } else {
      // V transposed store: vhT2[bh][lblk][d][l16]; tile covers one lblk.
      const int bq = rowBase >> 12;
      const int lblk = (rowBase & 4095) >> 8;
      ushort_t* base0 = Cb + (long)lblk * 16384;
#pragma unroll
      for (int i = 0; i < 8; ++i) {
        const int cid = i * 512 + t; // d fast, h slow -> coalesced stores
        const int d = cid & 255;
        const int h = cid >> 8;
        uint_t w[8];
#pragma unroll
        for (int j = 0; j < 8; ++j) {
          const int r0 = (2 * j) * 16 + h;
          const int r1 = (2 * j + 1) * 16 + h;
          const ushort_t v0 = sm[r0 * 256 + (((d >> 3) ^ (r0 & 7)) * 8) + (d & 7)];
          const ushort_t v1 = sm[r1 * 256 + (((d >> 3) ^ (r1 & 7)) * 8) + (d & 7)];
          w[j] = (uint_t)v0 | ((uint_t)v1 << 16);
        }
        ushort_t* dst = base0 + (long)(bq * 16 + h) * 262144 + (colBase + d) * 16;
        *(uint4*)dst = make_uint4(w[0], w[1], w[2], w[3]);
        *(uint4*)(dst + 8) = make_uint4(w[4], w[5], w[6], w[7]);
      }
    }
  }
#undef STAGE
#undef LDA4
#undef LDB2
#undef MMQ
}

extern "C" void kernel_launch(void* const* d_in, const int* in_sizes, int n_in,
                              void* d_out, int out_size, void* d_ws, size_t ws_size,
                              hipStream_t stream) {
  const float* q = (const float*)d_in[0];
  const float* k = (const float*)d_in[1];
  const float* v = (const float*)d_in[2];
  const int* mask = (const int*)d_in[3];
  const float* Wq = (const float*)d_in[4];
  const float* Wk = (const float*)d_in[5];
  const float* Wv = (const float*)d_in[6];
  const float* Wo = (const float*)d_in[7];
  float* out = (float*)d_out;

  char* ws = (char*)d_ws;
  const size_t MB = 1024 * 1024;
  ushort_t* WT = (ushort_t*)ws; // packed [4][1024][1024] bf16: Wq,Wk,Wv,Wo (8MB)

  const bool big = ws_size >= (size_t)200 * MB;

  if (big) {
    // layout: WT 0..8 | qkvb 8..104 | qh 104..136 | kh 136..168 | vhT2 168..200
    // after proj (qkvb dead): x 48..80
    ushort_t* qkvb = (ushort_t*)(ws + 8 * MB);
    ushort_t* qh = (ushort_t*)(ws + 104 * MB);
    ushort_t* kh = (ushort_t*)(ws + 136 * MB);
    ushort_t* vhT2 = (ushort_t*)(ws + 168 * MB);
    ushort_t* x = (ushort_t*)(ws + 48 * MB);

    prep<<<28672, 256, 0, stream>>>(q, k, v, Wq, Wk, Wv, Wo, (uint4*)qkvb, WT);
    // one batched dispatch: z=0/1 -> qh/kh proj-permute; z=2 -> vhT2 transposed
    gemm256<1><<<768, 512, 0, stream>>>(qkvb, qkvb + (size_t)16777216,
                                        qkvb + (size_t)33554432, WT, qh, 1 << 20,
                                        (long)16777216, 2);
    attn_fused<<<256, 256, 0, stream>>>(qh, kh, vhT2, mask, x);
    gemm256<0><<<256, 512, 0, stream>>>(x, x, x, WT + (size_t)3145728, out, 0, 0, -1);
  } else {
    // serial fallback (peak 168MB): WT 0..8 | qb 8..40 | qh 40..72 | kh 72..104
    // | vhT2 104..136 ; after proj: x 16..48
    ushort_t* qb = (ushort_t*)(ws + 8 * MB);
    ushort_t* qh = (ushort_t*)(ws + 40 * MB);
    ushort_t* kh = (ushort_t*)(ws + 72 * MB);
    ushort_t* vhT2 = (ushort_t*)(ws + 104 * MB);
    ushort_t* x = (ushort_t*)(ws + 16 * MB);

    prep<<<28672, 256, 0, stream>>>(q, k, v, Wq, Wk, Wv, Wo, (uint4*)qb, WT); // qb only z0 used below
    gemm256<1><<<256, 512, 0, stream>>>(qb, qb, qb, WT, qh, 0, 0, -1);
    // re-convert k and v serially into qb (prep wrote q only at z=0 slot; reuse full path)
    // Note: in fallback we simply re-run prep's cvt region per input via gemm input slots:
    gemm256<1><<<256, 512, 0, stream>>>(qb + (size_t)16777216, qb + (size_t)16777216,
                                        qb + (size_t)16777216, WT + (size_t)1048576, kh, 0, 0, -1);
    gemm256<1><<<256, 512, 0, stream>>>(qb + (size_t)33554432, qb + (size_t)33554432,
                                        qb + (size_t)33554432, WT + (size_t)2097152, vhT2, 0, 0, 0);
    attn_fused<<<256, 256, 0, stream>>>(qh, kh, vhT2, mask, x);
    gemm256<0><<<256, 512, 0, stream>>>(x, x, x, WT + (size_t)3145728, out, 0, 0, -1);
  }
}

// Round 14
// 250.472 us; speedup vs baseline: 1.3347x; 1.0247x over previous
//
#include <hip/hip_runtime.h>
#include <hip/hip_bf16.h>

typedef __bf16 bf16x8 __attribute__((ext_vector_type(8)));
typedef float f32x4 __attribute__((ext_vector_type(4)));
typedef unsigned short ushort_t;
typedef unsigned int uint_t;

#define HN 16
#define LSEQ 256
#define DD 1024
#define BB 4
#define SS 4096
#define MROWS (BB * SS) /* 16384 */
#define BHN (BB * HN)   /* 64 */

#define AS1 __attribute__((address_space(1)))
#define AS3 __attribute__((address_space(3)))

__device__ __forceinline__ ushort_t f2bf(float f) {
  uint_t u = __builtin_bit_cast(uint_t, f);
  u += 0x7fffu + ((u >> 16) & 1u); // RNE
  return (ushort_t)(u >> 16);
}
__device__ __forceinline__ uint_t pk2(float lo, float hi) {
  return (uint_t)f2bf(lo) | ((uint_t)f2bf(hi) << 16);
}

// ---------- prep: fp32->bf16 convert for q,k,v  +  packed weight transpose ----------
// blocks [0, 24576): cvt (z = bid/8192); blocks [24576, 28672): transpose W0..W3.
__global__ __launch_bounds__(256) void prep(const float* __restrict__ q,
                                            const float* __restrict__ k,
                                            const float* __restrict__ v,
                                            const float* __restrict__ W0,
                                            const float* __restrict__ W1,
                                            const float* __restrict__ W2,
                                            const float* __restrict__ W3,
                                            uint4* __restrict__ qkvb,
                                            ushort_t* __restrict__ WT) {
  const int bid = blockIdx.x;
  const int t = threadIdx.x;
  if (bid < 24576) {
    const int z = bid >> 13;
    const float4* in = (const float4*)((z == 0) ? q : (z == 1) ? k : v);
    const long i = (long)(bid & 8191) * 256 + t;
    const float4 a = in[i * 2];
    const float4 b = in[i * 2 + 1];
    uint4 o;
    o.x = pk2(a.x, a.y);
    o.y = pk2(a.z, a.w);
    o.z = pk2(b.x, b.y);
    o.w = pk2(b.z, b.w);
    qkvb[(long)z * 2097152 + i] = o;
  } else {
    __shared__ float tile[32][33];
    const int b2 = bid - 24576;
    const int z = b2 >> 10;
    const float* W = (z == 0) ? W0 : (z == 1) ? W1 : (z == 2) ? W2 : W3;
    ushort_t* dst = WT + (long)z * 1048576;
    const int rem = b2 & 1023;
    const int bn = (rem & 31) * 32, bk = (rem >> 5) * 32;
    const int tx = t & 31, ty = t >> 5;
#pragma unroll
    for (int j = 0; j < 32; j += 8)
      tile[ty + j][tx] = W[(long)(bk + ty + j) * DD + bn + tx];
    __syncthreads();
#pragma unroll
    for (int j = 0; j < 32; j += 8)
      dst[(long)(bn + ty + j) * DD + bk + tx] = f2bf(tile[tx][ty + j]);
  }
}

// ---------- cvt1: single input fp32->bf16 (fallback path) ----------
__global__ __launch_bounds__(256) void cvt1(const float4* __restrict__ in,
                                            uint4* __restrict__ out) {
  const long i = (long)blockIdx.x * 256 + threadIdx.x;
  const float4 a = in[i * 2];
  const float4 b = in[i * 2 + 1];
  uint4 o;
  o.x = pk2(a.x, a.y);
  o.y = pk2(a.z, a.w);
  o.z = pk2(b.x, b.y);
  o.w = pk2(b.z, b.w);
  out[i] = o;
}

// ---------- fused attention: scores + mask + softmax + PV (8 waves) ----------
// per block: one (b,h), 64 q-rows. Reads qh,kh (proj-permuted) and vhT2
// [bh][lblk][d][l16]; writes x[b*4096+l*16+h][d] bf16. LDS 112 KB, 512 thr.
__global__ __launch_bounds__(512, 1) void attn_fused(const ushort_t* __restrict__ qh,
                                                     const ushort_t* __restrict__ kh,
                                                     const ushort_t* __restrict__ vhT2,
                                                     const int* __restrict__ mask,
                                                     ushort_t* __restrict__ x) {
  __shared__ char smemraw[114688];
  ushort_t* sA = (ushort_t*)smemraw;            // score A staging: 2 x 4096 elems
  ushort_t* sB = (ushort_t*)(smemraw + 16384);  // score B staging: 2 x 16384 elems
  float* Sf = (float*)smemraw;                  // [64][256] fp32 (aliases staging)
  ushort_t* sPV = (ushort_t*)smemraw;           // PV B dbuf: 2 x 16384 elems (aliases)
  ushort_t* sC = (ushort_t*)(smemraw + 32768);  // PV C-stage [64][256] (aliases buf1)
  ushort_t* attL = (ushort_t*)(smemraw + 81920); // att [64][256] bf16, chunk-XOR swz

  const int orig = blockIdx.x;
  const int wgid = (orig & 7) * 32 + (orig >> 3); // XCD-chunked, 256 % 8 == 0
  const int bh = wgid >> 2, rb = wgid & 3;
  const int b = bh >> 4;
  const ushort_t* A = qh + ((long)bh * 256 + rb * 64) * 1024;
  const ushort_t* Bk = kh + (long)bh * 256 * 1024;
  const ushort_t* Vb = vhT2 + (long)bh * 262144;

  const int t = threadIdx.x, lane = t & 63, wid = t >> 6; // wid 0..7
  const int fr = lane & 15, q = lane >> 4;
  const int wc = wid * 32; // 32-col slice per wave
  const int sw0 = (q ^ (fr & 7)) * 8;
  const int sw1 = ((4 + q) ^ (fr & 7)) * 8;

  // score staging: A tile = 512 chunks (1/thread); B tile = 2048 chunks (4/thread)
  int srcAo, dstAo, srcBo[4], dstBo[4];
  {
    const int c = t, row = c >> 3, gc = (c & 7) ^ (row & 7);
    srcAo = row * 1024 + gc * 8;
    dstAo = (c & ~63) * 8;
  }
#pragma unroll
  for (int i = 0; i < 4; ++i) {
    const int c = i * 512 + t, row = c >> 3, gc = (c & 7) ^ (row & 7);
    srcBo[i] = row * 1024 + gc * 8;
    dstBo[i] = (c & ~63) * 8;
  }
  // PV B staging: 2048 chunks (4/thread)
  int pvOff[4], pvDst[4];
#pragma unroll
  for (int i = 0; i < 4; ++i) {
    const int c = i * 512 + t, dr = c >> 3, gc = (c & 7) ^ (dr & 7);
    pvOff[i] = (gc >> 1) * 16384 + dr * 16 + (gc & 1) * 8;
    pvDst[i] = (c & ~63) * 8;
  }

  auto stage = [&](int buf, int kt) {
    const int ko = kt * 64;
    __builtin_amdgcn_global_load_lds((const AS1 void*)(A + srcAo + ko),
                                     (AS3 void*)(sA + buf * 4096 + dstAo), 16, 0, 0);
#pragma unroll
    for (int i = 0; i < 4; ++i)
      __builtin_amdgcn_global_load_lds((const AS1 void*)(Bk + srcBo[i] + ko),
                                       (AS3 void*)(sB + buf * 16384 + dstBo[i]), 16, 0, 0);
  };

  f32x4 acc[4][2];
#pragma unroll
  for (int m = 0; m < 4; ++m)
#pragma unroll
    for (int n = 0; n < 2; ++n) acc[m][n] = (f32x4){0.f, 0.f, 0.f, 0.f};

  // ---- scores: S = qh_tile @ kh^T, K=1024 ----
  stage(0, 0);
  __syncthreads();
  int cur = 0;
  for (int kt = 0; kt < 16; ++kt) {
    if (kt < 15) stage(cur ^ 1, kt + 1);
    bf16x8 af[4][2], bfv[2][2];
    const ushort_t* bA = sA + cur * 4096;
    const ushort_t* bB = sB + cur * 16384;
#pragma unroll
    for (int m = 0; m < 4; ++m) {
      af[m][0] = *(const bf16x8*)(bA + (m * 16 + fr) * 64 + sw0);
      af[m][1] = *(const bf16x8*)(bA + (m * 16 + fr) * 64 + sw1);
    }
#pragma unroll
    for (int n = 0; n < 2; ++n) {
      bfv[n][0] = *(const bf16x8*)(bB + (wc + n * 16 + fr) * 64 + sw0);
      bfv[n][1] = *(const bf16x8*)(bB + (wc + n * 16 + fr) * 64 + sw1);
    }
#pragma unroll
    for (int m = 0; m < 4; ++m)
#pragma unroll
      for (int n = 0; n < 2; ++n) {
        acc[m][n] = __builtin_amdgcn_mfma_f32_16x16x32_bf16(af[m][0], bfv[n][0], acc[m][n], 0, 0, 0);
        acc[m][n] = __builtin_amdgcn_mfma_f32_16x16x32_bf16(af[m][1], bfv[n][1], acc[m][n], 0, 0, 0);
      }
    __syncthreads();
    cur ^= 1;
  }

  // raw S -> LDS fp32
#pragma unroll
  for (int m = 0; m < 4; ++m)
#pragma unroll
    for (int n = 0; n < 2; ++n)
#pragma unroll
      for (int r = 0; r < 4; ++r)
        Sf[(m * 16 + q * 4 + r) * 256 + wc + n * 16 + fr] = acc[m][n][r];
  __syncthreads();

  // ---- softmax (wave-per-row, 8 rows/wave), att -> LDS bf16 (chunk-XOR swz) ----
#pragma unroll 2
  for (int i = 0; i < 8; ++i) {
    const int row = wid * 8 + i;
    const int gl = rb * 64 + row;
    const f32x4 sv = *(const f32x4*)&Sf[row * 256 + lane * 4];
    const int4 mv = *(const int4*)&mask[((long)b * 256 + gl) * 256 + lane * 4];
    float s[4];
    s[0] = (mv.x == 0) ? 1e-9f : sv[0] * 0.03125f;
    s[1] = (mv.y == 0) ? 1e-9f : sv[1] * 0.03125f;
    s[2] = (mv.z == 0) ? 1e-9f : sv[2] * 0.03125f;
    s[3] = (mv.w == 0) ? 1e-9f : sv[3] * 0.03125f;
    float mx = fmaxf(fmaxf(s[0], s[1]), fmaxf(s[2], s[3]));
#pragma unroll
    for (int off = 32; off; off >>= 1) mx = fmaxf(mx, __shfl_xor(mx, off));
    float e[4], sum = 0.f;
#pragma unroll
    for (int j = 0; j < 4; ++j) {
      e[j] = __expf(s[j] - mx);
      sum += e[j];
    }
#pragma unroll
    for (int off = 32; off; off >>= 1) sum += __shfl_xor(sum, off);
    const float inv = 1.0f / sum;
    ushort4 o;
    o.x = f2bf(e[0] * inv);
    o.y = f2bf(e[1] * inv);
    o.z = f2bf(e[2] * inv);
    o.w = f2bf(e[3] * inv);
    const int mch = lane >> 1;
    *(ushort4*)(attL + row * 256 + (((mch ^ (row & 7)) << 3) + (lane & 1) * 4)) = o;
  }
  __syncthreads(); // att complete; Sf/staging dead -> PV may reuse [0,64K)

  // ---- PV: x[64][1024] = att @ vh, 4 d-blocks of 256, K=256 in 4 tiles ----
  const int r0 = t >> 3, qd = t & 7;
  const long orow = (long)((b << 12) + (rb * 64 + r0) * 16 + (bh & 15));
  for (int nb = 0; nb < 4; ++nb) {
#pragma unroll
    for (int m = 0; m < 4; ++m)
#pragma unroll
      for (int n = 0; n < 2; ++n) acc[m][n] = (f32x4){0.f, 0.f, 0.f, 0.f};

    // stage B tile0 (256d x 64m) into buf0
#pragma unroll
    for (int i = 0; i < 4; ++i)
      __builtin_amdgcn_global_load_lds((const AS1 void*)(Vb + pvOff[i] + nb * 4096),
                                       (AS3 void*)(sPV + pvDst[i]), 16, 0, 0);
    __syncthreads();

    int pbuf = 0;
    for (int mt = 0; mt < 4; ++mt) {
      if (mt < 3) {
#pragma unroll
        for (int i = 0; i < 4; ++i)
          __builtin_amdgcn_global_load_lds(
              (const AS1 void*)(Vb + pvOff[i] + (mt + 1) * 65536 + nb * 4096),
              (AS3 void*)(sPV + (pbuf ^ 1) * 16384 + pvDst[i]), 16, 0, 0);
      }
#pragma unroll
      for (int kk = 0; kk < 2; ++kk) {
        bf16x8 af[4], bfv[2];
#pragma unroll
        for (int m = 0; m < 4; ++m) {
          const int l = m * 16 + fr;
          af[m] = *(const bf16x8*)(attL + l * 256 + (((mt * 8 + kk * 4 + q) ^ (l & 7)) << 3));
        }
#pragma unroll
        for (int n = 0; n < 2; ++n) {
          const int dr = wc + n * 16 + fr;
          bfv[n] = *(const bf16x8*)(sPV + pbuf * 16384 + dr * 64 + (((kk * 4 + q) ^ (dr & 7)) << 3));
        }
#pragma unroll
        for (int m = 0; m < 4; ++m)
#pragma unroll
          for (int n = 0; n < 2; ++n)
            acc[m][n] = __builtin_amdgcn_mfma_f32_16x16x32_bf16(af[m], bfv[n], acc[m][n], 0, 0, 0);
      }
      __syncthreads();
      pbuf ^= 1;
    }

    // C-tile -> LDS (buf1 region, dead) with chunk-XOR; then coalesced permuted store
#pragma unroll
    for (int m = 0; m < 4; ++m)
#pragma unroll
      for (int n = 0; n < 2; ++n)
#pragma unroll
        for (int r = 0; r < 4; ++r) {
          const int row = m * 16 + q * 4 + r;
          const int col = wc + n * 16 + fr;
          sC[row * 256 + (((col >> 3) ^ (row & 7)) << 3) + (col & 7)] = f2bf(acc[m][n][r]);
        }
    __syncthreads();
    ushort_t* dst = x + orow * 1024 + nb * 256 + qd * 32;
#pragma unroll
    for (int j = 0; j < 4; ++j) {
      const int cc = qd * 4 + j;
      *(uint4*)(dst + j * 8) = *(const uint4*)(sC + r0 * 256 + ((cc ^ (r0 & 7)) << 3));
    }
    __syncthreads(); // C-read done before next nb overwrites bufs
  }
}

#define SBAR() asm volatile("s_barrier" ::: "memory")
#define LGKM0() asm volatile("s_waitcnt lgkmcnt(0)" ::: "memory")
#define VM(N) asm volatile("s_waitcnt vmcnt(" #N ")" ::: "memory")
#define PH_OPEN() SBAR(); LGKM0(); __builtin_amdgcn_s_setprio(1)
#define PH_CLOSE() __builtin_amdgcn_s_setprio(0); SBAR()

// ---------- 256^2 8-phase TN GEMM, z-batched, early-staged counted-vmcnt ----------
// SMODE 0 = fp32 direct; SMODE 1 = bf16 proj-permute, except z==vzsel which
// stores V transposed into vhT2[bh][lblk][d][l16] (coalesced 32B runs).
template <int SMODE>
__global__ __launch_bounds__(512, 1) void gemm256(const ushort_t* __restrict__ A0,
                                                  const ushort_t* __restrict__ A1,
                                                  const ushort_t* __restrict__ A2,
                                                  const ushort_t* __restrict__ Btp,
                                                  void* __restrict__ Cp, long bStrideZ,
                                                  long cStrideZ, int vzsel) {
  __shared__ ushort_t sm[65536]; // 128 KiB

  const int orig = blockIdx.x;
  const int cpx = (int)gridDim.x >> 3;
  const int wgid = (orig & 7) * cpx + (orig >> 3); // bijective (grid % 8 == 0)
  const int z = wgid >> 8;
  const int tile = wgid & 255;
  const int by = tile >> 2, bx = tile & 3;
  const int rowBase = by * 256, colBase = bx * 256;

  const ushort_t* Ab = (z == 0) ? A0 : (z == 1) ? A1 : A2;
  const ushort_t* Bt = Btp + bStrideZ * z;

  const int t = threadIdx.x;
  const int lane = t & 63;
  const int wid = t >> 6;
  const int wm = wid >> 2; // 0..1
  const int wn = wid & 3;  // 0..3
  const int fr = lane & 15;
  const int q = lane >> 4;

  const int sw0 = ((q ^ (fr & 7)) * 8);
  const int sw1 = (((4 + q) ^ (fr & 7)) * 8);
  const int aoff0 = fr * 64 + sw0;
  const int aoff1 = fr * 64 + sw1;
  const int bbase = ((wn & 1) * 64 + fr) * 64;
  const int boff0 = bbase + sw0;
  const int boff1 = bbase + sw1;

  const ushort_t* srcA[2][2];
  const ushort_t* srcB[2][2];
  int ldsoff[2];
#pragma unroll
  for (int i = 0; i < 2; ++i) {
    const int c = i * 512 + t;
    const int rowc = c >> 3;
    const int gc = (c & 7) ^ (rowc & 7);
    srcA[0][i] = Ab + (long)(rowBase + rowc) * 1024 + gc * 8;
    srcA[1][i] = Ab + (long)(rowBase + 128 + rowc) * 1024 + gc * 8;
    srcB[0][i] = Bt + (long)(colBase + rowc) * 1024 + gc * 8;
    srcB[1][i] = Bt + (long)(colBase + 128 + rowc) * 1024 + gc * 8;
    ldsoff[i] = (c & ~63) * 8;
  }

#define STAGE(kind, h, T)                                                                   \
  do {                                                                                      \
    ushort_t* _d = sm + ((kind) ? 32768 : 0) + ((T) & 1) * 16384 + (h) * 8192;              \
    const ushort_t* _s0 = ((kind) ? srcB[h][0] : srcA[h][0]) + (long)(T) * 64;              \
    __builtin_amdgcn_global_load_lds((const AS1 void*)_s0,                                  \
                                     (AS3 void*)(_d + ldsoff[0]), 16, 0, 0);                \
    const ushort_t* _s1 = ((kind) ? srcB[h][1] : srcA[h][1]) + (long)(T) * 64;              \
    __builtin_amdgcn_global_load_lds((const AS1 void*)_s1,                                  \
                                     (AS3 void*)(_d + ldsoff[1]), 16, 0, 0);                \
  } while (0)

  f32x4 acc[8][4];
#pragma unroll
  for (int m = 0; m < 8; ++m)
#pragma unroll
    for (int n = 0; n < 4; ++n) acc[m][n] = (f32x4){0.f, 0.f, 0.f, 0.f};

  bf16x8 af[4][2], bf0[2][2], bf1[2][2];

#define LDA4(dbuf, msub)                                                         \
  do {                                                                           \
    const ushort_t* _b = sm + (dbuf)*16384 + wm * 8192 + (msub)*4096;            \
    _Pragma("unroll") for (int m2 = 0; m2 < 4; ++m2) {                           \
      af[m2][0] = *(const bf16x8*)(_b + m2 * 1024 + aoff0);                      \
      af[m2][1] = *(const bf16x8*)(_b + m2 * 1024 + aoff1);                      \
    }                                                                            \
  } while (0)

#define LDB2(dbuf, nsub, bfv)                                                    \
  do {                                                                           \
    const ushort_t* _b = sm + 32768 + (dbuf)*16384 + (wn >> 1) * 8192 + (nsub)*2048; \
    _Pragma("unroll") for (int n2 = 0; n2 < 2; ++n2) {                           \
      bfv[n2][0] = *(const bf16x8*)(_b + n2 * 1024 + boff0);                     \
      bfv[n2][1] = *(const bf16x8*)(_b + n2 * 1024 + boff1);                     \
    }                                                                            \
  } while (0)

#define MMQ(msub, nsub, bfv)                                                     \
  do {                                                                           \
    _Pragma("unroll") for (int m2 = 0; m2 < 4; ++m2)                             \
        _Pragma("unroll") for (int n2 = 0; n2 < 2; ++n2) {                       \
      acc[(msub)*4 + m2][(nsub)*2 + n2] = __builtin_amdgcn_mfma_f32_16x16x32_bf16( \
          af[m2][0], bfv[n2][0], acc[(msub)*4 + m2][(nsub)*2 + n2], 0, 0, 0);    \
      acc[(msub)*4 + m2][(nsub)*2 + n2] = __builtin_amdgcn_mfma_f32_16x16x32_bf16( \
          af[m2][1], bfv[n2][1], acc[(msub)*4 + m2][(nsub)*2 + n2], 0, 0, 0);    \
    }                                                                            \
  } while (0)

  const int NT = 16; // K=1024, K-tiles of 64
  const int NI = 8;

  // prologue: tiles 0 and 1 fully staged; VM(8) drains ALL of tile0
  STAGE(0, 0, 0);
  STAGE(0, 1, 0);
  STAGE(1, 0, 0);
  STAGE(1, 1, 0);
  STAGE(0, 0, 1);
  STAGE(0, 1, 1);
  STAGE(1, 0, 1);
  STAGE(1, 1, 1);
  VM(8);
  SBAR();

  for (int it = 0; it < NI - 1; ++it) {
    const int T0 = 2 * it;
    LDA4(0, 0);
    LDB2(0, 0, bf0);
    PH_OPEN(); MMQ(0, 0, bf0); PH_CLOSE();
    LDB2(0, 1, bf1);
    PH_OPEN(); MMQ(0, 1, bf1); PH_CLOSE();
    LDA4(0, 1);
    STAGE(1, 0, T0 + 2);
    STAGE(1, 1, T0 + 2);
    PH_OPEN(); MMQ(1, 1, bf1); PH_CLOSE();
    STAGE(0, 0, T0 + 2);
    STAGE(0, 1, T0 + 2);
    SBAR();
    __builtin_amdgcn_s_setprio(1);
    MMQ(1, 0, bf0);
    __builtin_amdgcn_s_setprio(0);
    VM(8); // drains tile T0+1 (>=4 phases cover); leaves T0+2
    SBAR();
    LDA4(1, 0);
    LDB2(1, 0, bf0);
    PH_OPEN(); MMQ(0, 0, bf0); PH_CLOSE();
    LDB2(1, 1, bf1);
    PH_OPEN(); MMQ(0, 1, bf1); PH_CLOSE();
    LDA4(1, 1);
    STAGE(1, 0, T0 + 3);
    STAGE(1, 1, T0 + 3);
    PH_OPEN(); MMQ(1, 1, bf1); PH_CLOSE();
    STAGE(0, 0, T0 + 3);
    STAGE(0, 1, T0 + 3);
    SBAR();
    __builtin_amdgcn_s_setprio(1);
    MMQ(1, 0, bf0);
    __builtin_amdgcn_s_setprio(0);
    VM(8); // drains tile T0+2; leaves T0+3
    SBAR();
  }

  { // peeled last iteration (tiles 14,15): no new stages
    LDA4(0, 0);
    LDB2(0, 0, bf0);
    PH_OPEN(); MMQ(0, 0, bf0); PH_CLOSE();
    LDB2(0, 1, bf1);
    PH_OPEN(); MMQ(0, 1, bf1); PH_CLOSE();
    LDA4(0, 1);
    PH_OPEN(); MMQ(1, 1, bf1); PH_CLOSE();
    SBAR();
    __builtin_amdgcn_s_setprio(1);
    MMQ(1, 0, bf0);
    __builtin_amdgcn_s_setprio(0);
    VM(0); // drains tile15 (>=4 phases cover)
    SBAR();
    LDA4(1, 0);
    LDB2(1, 0, bf0);
    PH_OPEN(); MMQ(0, 0, bf0); PH_CLOSE();
    LDB2(1, 1, bf1);
    PH_OPEN(); MMQ(0, 1, bf1); PH_CLOSE();
    LDA4(1, 1);
    PH_OPEN(); MMQ(1, 1, bf1); PH_CLOSE();
    SBAR();
    MMQ(1, 0, bf0);
    SBAR();
  }

  const int rq = q * 4;
  if constexpr (SMODE == 0) {
    float* Cf = (float*)Cp + cStrideZ * z;
#pragma unroll
    for (int m = 0; m < 8; ++m)
#pragma unroll
      for (int n = 0; n < 4; ++n)
#pragma unroll
        for (int r = 0; r < 4; ++r) {
          const int row = rowBase + wm * 128 + m * 16 + rq + r;
          const int col = colBase + wn * 64 + n * 16 + fr;
          Cf[(long)row * 1024 + col] = acc[m][n][r];
        }
  } else {
    // swizzled C-tile in LDS (shared by both permute variants)
#pragma unroll
    for (int m = 0; m < 8; ++m)
#pragma unroll
      for (int n = 0; n < 4; ++n)
#pragma unroll
        for (int r = 0; r < 4; ++r) {
          const int row = wm * 128 + m * 16 + rq + r;
          const int col = wn * 64 + n * 16 + fr;
          sm[row * 256 + (((col >> 3) ^ (row & 7)) * 8) + (col & 7)] = f2bf(acc[m][n][r]);
        }
    __syncthreads();
    ushort_t* Cb = (ushort_t*)Cp + cStrideZ * z;
    if (z != vzsel) {
      // proj-permute: row grow = b*4096 + s, s = l*16+h -> (b*16+h)*256 + l
      const int cc = t & 31;
      const int r0 = t >> 5;
#pragma unroll
      for (int i = 0; i < 16; ++i) {
        const int row = r0 + i * 16;
        const uint4 val = *(const uint4*)(sm + row * 256 + ((cc ^ (row & 7)) * 8));
        const int grow = rowBase + row;
        const int b = grow >> 12;
        const int s = grow & 4095;
        const int orow = ((b << 4) + (s & 15)) * 256 + (s >> 4);
        *(uint4*)(Cb + (long)orow * 1024 + colBase + cc * 8) = val;
      }
    } else {
      // V transposed store: vhT2[bh][lblk][d][l16]; tile covers one lblk.
      const int bq = rowBase >> 12;
      const int lblk = (rowBase & 4095) >> 8;
      ushort_t* base0 = Cb + (long)lblk * 16384;
#pragma unroll
      for (int i = 0; i < 8; ++i) {
        const int cid = i * 512 + t; // d fast, h slow -> coalesced stores
        const int d = cid & 255;
        const int h = cid >> 8;
        uint_t w[8];
#pragma unroll
        for (int j = 0; j < 8; ++j) {
          const int r0 = (2 * j) * 16 + h;
          const int r1 = (2 * j + 1) * 16 + h;
          const ushort_t v0 = sm[r0 * 256 + (((d >> 3) ^ (r0 & 7)) * 8) + (d & 7)];
          const ushort_t v1 = sm[r1 * 256 + (((d >> 3) ^ (r1 & 7)) * 8) + (d & 7)];
          w[j] = (uint_t)v0 | ((uint_t)v1 << 16);
        }
        ushort_t* dst = base0 + (long)(bq * 16 + h) * 262144 + (colBase + d) * 16;
        *(uint4*)dst = make_uint4(w[0], w[1], w[2], w[3]);
        *(uint4*)(dst + 8) = make_uint4(w[4], w[5], w[6], w[7]);
      }
    }
  }
#undef STAGE
#undef LDA4
#undef LDB2
#undef MMQ
}

extern "C" void kernel_launch(void* const* d_in, const int* in_sizes, int n_in,
                              void* d_out, int out_size, void* d_ws, size_t ws_size,
                              hipStream_t stream) {
  const float* q = (const float*)d_in[0];
  const float* k = (const float*)d_in[1];
  const float* v = (const float*)d_in[2];
  const int* mask = (const int*)d_in[3];
  const float* Wq = (const float*)d_in[4];
  const float* Wk = (const float*)d_in[5];
  const float* Wv = (const float*)d_in[6];
  const float* Wo = (const float*)d_in[7];
  float* out = (float*)d_out;

  char* ws = (char*)d_ws;
  const size_t MB = 1024 * 1024;
  ushort_t* WT = (ushort_t*)ws; // packed [4][1024][1024] bf16: Wq,Wk,Wv,Wo (8MB)

  const bool big = ws_size >= (size_t)200 * MB;

  if (big) {
    // layout: WT 0..8 | qkvb 8..104 | qh 104..136 | kh 136..168 | vhT2 168..200
    // after proj (qkvb dead): x 48..80
    ushort_t* qkvb = (ushort_t*)(ws + 8 * MB);
    ushort_t* qh = (ushort_t*)(ws + 104 * MB);
    ushort_t* kh = (ushort_t*)(ws + 136 * MB);
    ushort_t* vhT2 = (ushort_t*)(ws + 168 * MB);
    ushort_t* x = (ushort_t*)(ws + 48 * MB);

    prep<<<28672, 256, 0, stream>>>(q, k, v, Wq, Wk, Wv, Wo, (uint4*)qkvb, WT);
    // one batched dispatch: z=0/1 -> qh/kh proj-permute; z=2 -> vhT2 transposed
    gemm256<1><<<768, 512, 0, stream>>>(qkvb, qkvb + (size_t)16777216,
                                        qkvb + (size_t)33554432, WT, qh, 1 << 20,
                                        (long)16777216, 2);
    attn_fused<<<256, 512, 0, stream>>>(qh, kh, vhT2, mask, x);
    gemm256<0><<<256, 512, 0, stream>>>(x, x, x, WT + (size_t)3145728, out, 0, 0, -1);
  } else {
    // serial fallback (peak 168MB): WT 0..8 | qb 8..40 | qh 40..72 | kh 72..104
    // | vhT2 104..136 ; after proj: x 16..48
    ushort_t* qb = (ushort_t*)(ws + 8 * MB);
    ushort_t* qh = (ushort_t*)(ws + 40 * MB);
    ushort_t* kh = (ushort_t*)(ws + 72 * MB);
    ushort_t* vhT2 = (ushort_t*)(ws + 104 * MB);
    ushort_t* x = (ushort_t*)(ws + 16 * MB);

    // transpose weights via prep's W-range only (blocks 24576..28671 shifted to 0..4095)
    // simpler: dedicated cvt1 per input + reuse prep for weights via full grid is wasteful;
    // here we just call prep's W part through a 4-block-range trick is fragile, so:
    prep<<<28672, 256, 0, stream>>>(q, k, v, Wq, Wk, Wv, Wo, (uint4*)qb, WT);
    // qb now holds bf16 q only up to 32MB region? prep writes all three z slots; qb is
    // 32MB here so only z=0 fits -> do serial cvt1 for each input instead:
    cvt1<<<8192, 256, 0, stream>>>((const float4*)q, (uint4*)qb);
    gemm256<1><<<256, 512, 0, stream>>>(qb, qb, qb, WT, qh, 0, 0, -1);
    cvt1<<<8192, 256, 0, stream>>>((const float4*)k, (uint4*)qb);
    gemm256<1><<<256, 512, 0, stream>>>(qb, qb, qb, WT + (size_t)1048576, kh, 0, 0, -1);
    cvt1<<<8192, 256, 0, stream>>>((const float4*)v, (uint4*)qb);
    gemm256<1><<<256, 512, 0, stream>>>(qb, qb, qb, WT + (size_t)2097152, vhT2, 0, 0, 0);
    attn_fused<<<256, 512, 0, stream>>>(qh, kh, vhT2, mask, x);
    gemm256<0><<<256, 512, 0, stream>>>(x, x, x, WT + (size_t)3145728, out, 0, 0, -1);
  }
}

// Round 15
// 248.179 us; speedup vs baseline: 1.3471x; 1.0092x over previous
//
#include <hip/hip_runtime.h>
#include <hip/hip_bf16.h>

typedef __bf16 bf16x8 __attribute__((ext_vector_type(8)));
typedef float f32x4 __attribute__((ext_vector_type(4)));
typedef unsigned short ushort_t;
typedef unsigned int uint_t;

#define HN 16
#define LSEQ 256
#define DD 1024
#define BB 4
#define SS 4096
#define MROWS (BB * SS) /* 16384 */
#define BHN (BB * HN)   /* 64 */

#define AS1 __attribute__((address_space(1)))
#define AS3 __attribute__((address_space(3)))

__device__ __forceinline__ ushort_t f2bf(float f) {
  uint_t u = __builtin_bit_cast(uint_t, f);
  u += 0x7fffu + ((u >> 16) & 1u); // RNE
  return (ushort_t)(u >> 16);
}
__device__ __forceinline__ uint_t pk2(float lo, float hi) {
  return (uint_t)f2bf(lo) | ((uint_t)f2bf(hi) << 16);
}

// ---------- prep: fp32->bf16 convert for q,k,v  +  packed weight transpose ----------
// blocks [0, 24576): cvt (z = bid/8192); blocks [24576, 28672): transpose W0..W3.
__global__ __launch_bounds__(256) void prep(const float* __restrict__ q,
                                            const float* __restrict__ k,
                                            const float* __restrict__ v,
                                            const float* __restrict__ W0,
                                            const float* __restrict__ W1,
                                            const float* __restrict__ W2,
                                            const float* __restrict__ W3,
                                            uint4* __restrict__ qkvb,
                                            ushort_t* __restrict__ WT) {
  const int bid = blockIdx.x;
  const int t = threadIdx.x;
  if (bid < 24576) {
    const int z = bid >> 13;
    const float4* in = (const float4*)((z == 0) ? q : (z == 1) ? k : v);
    const long i = (long)(bid & 8191) * 256 + t;
    const float4 a = in[i * 2];
    const float4 b = in[i * 2 + 1];
    uint4 o;
    o.x = pk2(a.x, a.y);
    o.y = pk2(a.z, a.w);
    o.z = pk2(b.x, b.y);
    o.w = pk2(b.z, b.w);
    qkvb[(long)z * 2097152 + i] = o;
  } else {
    __shared__ float tile[32][33];
    const int b2 = bid - 24576;
    const int z = b2 >> 10;
    const float* W = (z == 0) ? W0 : (z == 1) ? W1 : (z == 2) ? W2 : W3;
    ushort_t* dst = WT + (long)z * 1048576;
    const int rem = b2 & 1023;
    const int bn = (rem & 31) * 32, bk = (rem >> 5) * 32;
    const int tx = t & 31, ty = t >> 5;
#pragma unroll
    for (int j = 0; j < 32; j += 8)
      tile[ty + j][tx] = W[(long)(bk + ty + j) * DD + bn + tx];
    __syncthreads();
#pragma unroll
    for (int j = 0; j < 32; j += 8)
      dst[(long)(bn + ty + j) * DD + bk + tx] = f2bf(tile[tx][ty + j]);
  }
}

// ---------- cvt1: single input fp32->bf16 (fallback path) ----------
__global__ __launch_bounds__(256) void cvt1(const float4* __restrict__ in,
                                            uint4* __restrict__ out) {
  const long i = (long)blockIdx.x * 256 + threadIdx.x;
  const float4 a = in[i * 2];
  const float4 b = in[i * 2 + 1];
  uint4 o;
  o.x = pk2(a.x, a.y);
  o.y = pk2(a.z, a.w);
  o.z = pk2(b.x, b.y);
  o.w = pk2(b.z, b.w);
  out[i] = o;
}

// ---------- weight transpose x4 (fallback path) ----------
__global__ __launch_bounds__(256) void transpose_w4(const float* __restrict__ W0,
                                                    const float* __restrict__ W1,
                                                    const float* __restrict__ W2,
                                                    const float* __restrict__ W3,
                                                    ushort_t* __restrict__ WT) {
  __shared__ float tile[32][33];
  const int z = blockIdx.z;
  const float* W = (z == 0) ? W0 : (z == 1) ? W1 : (z == 2) ? W2 : W3;
  ushort_t* dst = WT + (long)z * 1048576;
  const int tx = threadIdx.x & 31, ty = threadIdx.x >> 5;
  const int bn = blockIdx.x * 32, bk = blockIdx.y * 32;
#pragma unroll
  for (int j = 0; j < 32; j += 8)
    tile[ty + j][tx] = W[(long)(bk + ty + j) * DD + bn + tx];
  __syncthreads();
#pragma unroll
  for (int j = 0; j < 32; j += 8)
    dst[(long)(bn + ty + j) * DD + bk + tx] = f2bf(tile[tx][ty + j]);
}

// ---------- fused attention: scores + mask + softmax + PV (8 waves) ----------
__global__ __launch_bounds__(512, 1) void attn_fused(const ushort_t* __restrict__ qh,
                                                     const ushort_t* __restrict__ kh,
                                                     const ushort_t* __restrict__ vhT2,
                                                     const int* __restrict__ mask,
                                                     ushort_t* __restrict__ x) {
  __shared__ char smemraw[114688];
  ushort_t* sA = (ushort_t*)smemraw;             // score A staging: 2 x 4096 elems
  ushort_t* sB = (ushort_t*)(smemraw + 16384);   // score B staging: 2 x 16384 elems
  float* Sf = (float*)smemraw;                   // [64][256] fp32 (aliases staging)
  ushort_t* sPV = (ushort_t*)smemraw;            // PV B dbuf: 2 x 16384 elems (aliases)
  ushort_t* sC = (ushort_t*)(smemraw + 32768);   // PV C-stage [64][256] (aliases buf1)
  ushort_t* attL = (ushort_t*)(smemraw + 81920); // att [64][256] bf16, chunk-XOR swz

  const int orig = blockIdx.x;
  const int wgid = (orig & 7) * 32 + (orig >> 3); // XCD-chunked, 256 % 8 == 0
  const int bh = wgid >> 2, rb = wgid & 3;
  const int b = bh >> 4;
  const ushort_t* A = qh + ((long)bh * 256 + rb * 64) * 1024;
  const ushort_t* Bk = kh + (long)bh * 256 * 1024;
  const ushort_t* Vb = vhT2 + (long)bh * 262144;

  const int t = threadIdx.x, lane = t & 63, wid = t >> 6; // wid 0..7
  const int fr = lane & 15, q = lane >> 4;
  const int wc = wid * 32; // 32-col slice per wave
  const int sw0 = (q ^ (fr & 7)) * 8;
  const int sw1 = ((4 + q) ^ (fr & 7)) * 8;

  // score staging: A tile = 512 chunks (1/thread); B tile = 2048 chunks (4/thread)
  int srcAo, dstAo, srcBo[4], dstBo[4];
  {
    const int c = t, row = c >> 3, gc = (c & 7) ^ (row & 7);
    srcAo = row * 1024 + gc * 8;
    dstAo = (c & ~63) * 8;
  }
#pragma unroll
  for (int i = 0; i < 4; ++i) {
    const int c = i * 512 + t, row = c >> 3, gc = (c & 7) ^ (row & 7);
    srcBo[i] = row * 1024 + gc * 8;
    dstBo[i] = (c & ~63) * 8;
  }
  // PV B staging: 2048 chunks (4/thread)
  int pvOff[4], pvDst[4];
#pragma unroll
  for (int i = 0; i < 4; ++i) {
    const int c = i * 512 + t, dr = c >> 3, gc = (c & 7) ^ (dr & 7);
    pvOff[i] = (gc >> 1) * 16384 + dr * 16 + (gc & 1) * 8;
    pvDst[i] = (c & ~63) * 8;
  }

  auto stage = [&](int buf, int kt) {
    const int ko = kt * 64;
    __builtin_amdgcn_global_load_lds((const AS1 void*)(A + srcAo + ko),
                                     (AS3 void*)(sA + buf * 4096 + dstAo), 16, 0, 0);
#pragma unroll
    for (int i = 0; i < 4; ++i)
      __builtin_amdgcn_global_load_lds((const AS1 void*)(Bk + srcBo[i] + ko),
                                       (AS3 void*)(sB + buf * 16384 + dstBo[i]), 16, 0, 0);
  };

  f32x4 acc[4][2];
#pragma unroll
  for (int m = 0; m < 4; ++m)
#pragma unroll
    for (int n = 0; n < 2; ++n) acc[m][n] = (f32x4){0.f, 0.f, 0.f, 0.f};

  // ---- scores: S = qh_tile @ kh^T, K=1024 ----
  stage(0, 0);
  __syncthreads();
  int cur = 0;
  for (int kt = 0; kt < 16; ++kt) {
    if (kt < 15) stage(cur ^ 1, kt + 1);
    bf16x8 af[4][2], bfv[2][2];
    const ushort_t* bA = sA + cur * 4096;
    const ushort_t* bB = sB + cur * 16384;
#pragma unroll
    for (int m = 0; m < 4; ++m) {
      af[m][0] = *(const bf16x8*)(bA + (m * 16 + fr) * 64 + sw0);
      af[m][1] = *(const bf16x8*)(bA + (m * 16 + fr) * 64 + sw1);
    }
#pragma unroll
    for (int n = 0; n < 2; ++n) {
      bfv[n][0] = *(const bf16x8*)(bB + (wc + n * 16 + fr) * 64 + sw0);
      bfv[n][1] = *(const bf16x8*)(bB + (wc + n * 16 + fr) * 64 + sw1);
    }
#pragma unroll
    for (int m = 0; m < 4; ++m)
#pragma unroll
      for (int n = 0; n < 2; ++n) {
        acc[m][n] = __builtin_amdgcn_mfma_f32_16x16x32_bf16(af[m][0], bfv[n][0], acc[m][n], 0, 0, 0);
        acc[m][n] = __builtin_amdgcn_mfma_f32_16x16x32_bf16(af[m][1], bfv[n][1], acc[m][n], 0, 0, 0);
      }
    __syncthreads();
    cur ^= 1;
  }

  // raw S -> LDS fp32
#pragma unroll
  for (int m = 0; m < 4; ++m)
#pragma unroll
    for (int n = 0; n < 2; ++n)
#pragma unroll
      for (int r = 0; r < 4; ++r)
        Sf[(m * 16 + q * 4 + r) * 256 + wc + n * 16 + fr] = acc[m][n][r];
  __syncthreads();

  // ---- softmax (wave-per-row, 8 rows/wave), att -> LDS bf16 (chunk-XOR swz) ----
#pragma unroll 2
  for (int i = 0; i < 8; ++i) {
    const int row = wid * 8 + i;
    const int gl = rb * 64 + row;
    const f32x4 sv = *(const f32x4*)&Sf[row * 256 + lane * 4];
    const int4 mv = *(const int4*)&mask[((long)b * 256 + gl) * 256 + lane * 4];
    float s[4];
    s[0] = (mv.x == 0) ? 1e-9f : sv[0] * 0.03125f;
    s[1] = (mv.y == 0) ? 1e-9f : sv[1] * 0.03125f;
    s[2] = (mv.z == 0) ? 1e-9f : sv[2] * 0.03125f;
    s[3] = (mv.w == 0) ? 1e-9f : sv[3] * 0.03125f;
    float mx = fmaxf(fmaxf(s[0], s[1]), fmaxf(s[2], s[3]));
#pragma unroll
    for (int off = 32; off; off >>= 1) mx = fmaxf(mx, __shfl_xor(mx, off));
    float e[4], sum = 0.f;
#pragma unroll
    for (int j = 0; j < 4; ++j) {
      e[j] = __expf(s[j] - mx);
      sum += e[j];
    }
#pragma unroll
    for (int off = 32; off; off >>= 1) sum += __shfl_xor(sum, off);
    const float inv = 1.0f / sum;
    ushort4 o;
    o.x = f2bf(e[0] * inv);
    o.y = f2bf(e[1] * inv);
    o.z = f2bf(e[2] * inv);
    o.w = f2bf(e[3] * inv);
    const int mch = lane >> 1;
    *(ushort4*)(attL + row * 256 + (((mch ^ (row & 7)) << 3) + (lane & 1) * 4)) = o;
  }
  __syncthreads(); // att complete; Sf/staging dead -> PV may reuse [0,64K)

  // ---- PV: x[64][1024] = att @ vh, 4 d-blocks of 256, K=256 in 4 tiles ----
  const int r0 = t >> 3, qd = t & 7;
  const long orow = (long)((b << 12) + (rb * 64 + r0) * 16 + (bh & 15));
  for (int nb = 0; nb < 4; ++nb) {
#pragma unroll
    for (int m = 0; m < 4; ++m)
#pragma unroll
      for (int n = 0; n < 2; ++n) acc[m][n] = (f32x4){0.f, 0.f, 0.f, 0.f};

#pragma unroll
    for (int i = 0; i < 4; ++i)
      __builtin_amdgcn_global_load_lds((const AS1 void*)(Vb + pvOff[i] + nb * 4096),
                                       (AS3 void*)(sPV + pvDst[i]), 16, 0, 0);
    __syncthreads();

    int pbuf = 0;
    for (int mt = 0; mt < 4; ++mt) {
      if (mt < 3) {
#pragma unroll
        for (int i = 0; i < 4; ++i)
          __builtin_amdgcn_global_load_lds(
              (const AS1 void*)(Vb + pvOff[i] + (mt + 1) * 65536 + nb * 4096),
              (AS3 void*)(sPV + (pbuf ^ 1) * 16384 + pvDst[i]), 16, 0, 0);
      }
#pragma unroll
      for (int kk = 0; kk < 2; ++kk) {
        bf16x8 af[4], bfv[2];
#pragma unroll
        for (int m = 0; m < 4; ++m) {
          const int l = m * 16 + fr;
          af[m] = *(const bf16x8*)(attL + l * 256 + (((mt * 8 + kk * 4 + q) ^ (l & 7)) << 3));
        }
#pragma unroll
        for (int n = 0; n < 2; ++n) {
          const int dr = wc + n * 16 + fr;
          bfv[n] = *(const bf16x8*)(sPV + pbuf * 16384 + dr * 64 + (((kk * 4 + q) ^ (dr & 7)) << 3));
        }
#pragma unroll
        for (int m = 0; m < 4; ++m)
#pragma unroll
          for (int n = 0; n < 2; ++n)
            acc[m][n] = __builtin_amdgcn_mfma_f32_16x16x32_bf16(af[m], bfv[n], acc[m][n], 0, 0, 0);
      }
      __syncthreads();
      pbuf ^= 1;
    }

    // C-tile -> LDS (buf1 region, dead) with chunk-XOR; then coalesced permuted store
#pragma unroll
    for (int m = 0; m < 4; ++m)
#pragma unroll
      for (int n = 0; n < 2; ++n)
#pragma unroll
        for (int r = 0; r < 4; ++r) {
          const int row = m * 16 + q * 4 + r;
          const int col = wc + n * 16 + fr;
          sC[row * 256 + (((col >> 3) ^ (row & 7)) << 3) + (col & 7)] = f2bf(acc[m][n][r]);
        }
    __syncthreads();
    ushort_t* dst = x + orow * 1024 + nb * 256 + qd * 32;
#pragma unroll
    for (int j = 0; j < 4; ++j) {
      const int cc = qd * 4 + j;
      *(uint4*)(dst + j * 8) = *(const uint4*)(sC + r0 * 256 + ((cc ^ (r0 & 7)) << 3));
    }
    __syncthreads(); // C-read done before next nb overwrites bufs
  }
}

#define SBAR() asm volatile("s_barrier" ::: "memory")
#define LGKM0() asm volatile("s_waitcnt lgkmcnt(0)" ::: "memory")
#define VM(N) asm volatile("s_waitcnt vmcnt(" #N ")" ::: "memory")
#define PH_OPEN() SBAR(); LGKM0(); __builtin_amdgcn_s_setprio(1)
#define PH_CLOSE() __builtin_amdgcn_s_setprio(0); SBAR()

// ---------- 256^2 8-phase TN GEMM, z-batched, early-staged counted-vmcnt ----------
// SMODE 0 = fp32 coalesced (quarter-staged LDS transpose); SMODE 1 = bf16
// proj-permute, except z==vzsel which stores V transposed into vhT2.
template <int SMODE>
__global__ __launch_bounds__(512, 1) void gemm256(const ushort_t* __restrict__ A0,
                                                  const ushort_t* __restrict__ A1,
                                                  const ushort_t* __restrict__ A2,
                                                  const ushort_t* __restrict__ Btp,
                                                  void* __restrict__ Cp, long bStrideZ,
                                                  long cStrideZ, int vzsel) {
  __shared__ ushort_t sm[65536]; // 128 KiB

  const int orig = blockIdx.x;
  const int cpx = (int)gridDim.x >> 3;
  const int wgid = (orig & 7) * cpx + (orig >> 3); // bijective (grid % 8 == 0)
  const int z = wgid >> 8;
  const int tile = wgid & 255;
  const int by = tile >> 2, bx = tile & 3;
  const int rowBase = by * 256, colBase = bx * 256;

  const ushort_t* Ab = (z == 0) ? A0 : (z == 1) ? A1 : A2;
  const ushort_t* Bt = Btp + bStrideZ * z;

  const int t = threadIdx.x;
  const int lane = t & 63;
  const int wid = t >> 6;
  const int wm = wid >> 2; // 0..1
  const int wn = wid & 3;  // 0..3
  const int fr = lane & 15;
  const int q = lane >> 4;

  const int sw0 = ((q ^ (fr & 7)) * 8);
  const int sw1 = (((4 + q) ^ (fr & 7)) * 8);
  const int aoff0 = fr * 64 + sw0;
  const int aoff1 = fr * 64 + sw1;
  const int bbase = ((wn & 1) * 64 + fr) * 64;
  const int boff0 = bbase + sw0;
  const int boff1 = bbase + sw1;

  const ushort_t* srcA[2][2];
  const ushort_t* srcB[2][2];
  int ldsoff[2];
#pragma unroll
  for (int i = 0; i < 2; ++i) {
    const int c = i * 512 + t;
    const int rowc = c >> 3;
    const int gc = (c & 7) ^ (rowc & 7);
    srcA[0][i] = Ab + (long)(rowBase + rowc) * 1024 + gc * 8;
    srcA[1][i] = Ab + (long)(rowBase + 128 + rowc) * 1024 + gc * 8;
    srcB[0][i] = Bt + (long)(colBase + rowc) * 1024 + gc * 8;
    srcB[1][i] = Bt + (long)(colBase + 128 + rowc) * 1024 + gc * 8;
    ldsoff[i] = (c & ~63) * 8;
  }

#define STAGE(kind, h, T)                                                                   \
  do {                                                                                      \
    ushort_t* _d = sm + ((kind) ? 32768 : 0) + ((T) & 1) * 16384 + (h) * 8192;              \
    const ushort_t* _s0 = ((kind) ? srcB[h][0] : srcA[h][0]) + (long)(T) * 64;              \
    __builtin_amdgcn_global_load_lds((const AS1 void*)_s0,                                  \
                                     (AS3 void*)(_d + ldsoff[0]), 16, 0, 0);                \
    const ushort_t* _s1 = ((kind) ? srcB[h][1] : srcA[h][1]) + (long)(T) * 64;              \
    __builtin_amdgcn_global_load_lds((const AS1 void*)_s1,                                  \
                                     (AS3 void*)(_d + ldsoff[1]), 16, 0, 0);                \
  } while (0)

  f32x4 acc[8][4];
#pragma unroll
  for (int m = 0; m < 8; ++m)
#pragma unroll
    for (int n = 0; n < 4; ++n) acc[m][n] = (f32x4){0.f, 0.f, 0.f, 0.f};

  bf16x8 af[4][2], bf0[2][2], bf1[2][2];

#define LDA4(dbuf, msub)                                                         \
  do {                                                                           \
    const ushort_t* _b = sm + (dbuf)*16384 + wm * 8192 + (msub)*4096;            \
    _Pragma("unroll") for (int m2 = 0; m2 < 4; ++m2) {                           \
      af[m2][0] = *(const bf16x8*)(_b + m2 * 1024 + aoff0);                      \
      af[m2][1] = *(const bf16x8*)(_b + m2 * 1024 + aoff1);                      \
    }                                                                            \
  } while (0)

#define LDB2(dbuf, nsub, bfv)                                                    \
  do {                                                                           \
    const ushort_t* _b = sm + 32768 + (dbuf)*16384 + (wn >> 1) * 8192 + (nsub)*2048; \
    _Pragma("unroll") for (int n2 = 0; n2 < 2; ++n2) {                           \
      bfv[n2][0] = *(const bf16x8*)(_b + n2 * 1024 + boff0);                     \
      bfv[n2][1] = *(const bf16x8*)(_b + n2 * 1024 + boff1);                     \
    }                                                                            \
  } while (0)

#define MMQ(msub, nsub, bfv)                                                     \
  do {                                                                           \
    _Pragma("unroll") for (int m2 = 0; m2 < 4; ++m2)                             \
        _Pragma("unroll") for (int n2 = 0; n2 < 2; ++n2) {                       \
      acc[(msub)*4 + m2][(nsub)*2 + n2] = __builtin_amdgcn_mfma_f32_16x16x32_bf16( \
          af[m2][0], bfv[n2][0], acc[(msub)*4 + m2][(nsub)*2 + n2], 0, 0, 0);    \
      acc[(msub)*4 + m2][(nsub)*2 + n2] = __builtin_amdgcn_mfma_f32_16x16x32_bf16( \
          af[m2][1], bfv[n2][1], acc[(msub)*4 + m2][(nsub)*2 + n2], 0, 0, 0);    \
    }                                                                            \
  } while (0)

  const int NT = 16; // K=1024, K-tiles of 64
  const int NI = 8;

  // prologue: tiles 0 and 1 fully staged; VM(8) drains ALL of tile0
  STAGE(0, 0, 0);
  STAGE(0, 1, 0);
  STAGE(1, 0, 0);
  STAGE(1, 1, 0);
  STAGE(0, 0, 1);
  STAGE(0, 1, 1);
  STAGE(1, 0, 1);
  STAGE(1, 1, 1);
  VM(8);
  SBAR();

  for (int it = 0; it < NI - 1; ++it) {
    const int T0 = 2 * it;
    LDA4(0, 0);
    LDB2(0, 0, bf0);
    PH_OPEN(); MMQ(0, 0, bf0); PH_CLOSE();
    LDB2(0, 1, bf1);
    PH_OPEN(); MMQ(0, 1, bf1); PH_CLOSE();
    LDA4(0, 1);
    STAGE(1, 0, T0 + 2);
    STAGE(1, 1, T0 + 2);
    PH_OPEN(); MMQ(1, 1, bf1); PH_CLOSE();
    STAGE(0, 0, T0 + 2);
    STAGE(0, 1, T0 + 2);
    SBAR();
    __builtin_amdgcn_s_setprio(1);
    MMQ(1, 0, bf0);
    __builtin_amdgcn_s_setprio(0);
    VM(8); // drains tile T0+1 (>=4 phases cover); leaves T0+2
    SBAR();
    LDA4(1, 0);
    LDB2(1, 0, bf0);
    PH_OPEN(); MMQ(0, 0, bf0); PH_CLOSE();
    LDB2(1, 1, bf1);
    PH_OPEN(); MMQ(0, 1, bf1); PH_CLOSE();
    LDA4(1, 1);
    STAGE(1, 0, T0 + 3);
    STAGE(1, 1, T0 + 3);
    PH_OPEN(); MMQ(1, 1, bf1); PH_CLOSE();
    STAGE(0, 0, T0 + 3);
    STAGE(0, 1, T0 + 3);
    SBAR();
    __builtin_amdgcn_s_setprio(1);
    MMQ(1, 0, bf0);
    __builtin_amdgcn_s_setprio(0);
    VM(8); // drains tile T0+2; leaves T0+3
    SBAR();
  }

  { // peeled last iteration (tiles 14,15): no new stages
    LDA4(0, 0);
    LDB2(0, 0, bf0);
    PH_OPEN(); MMQ(0, 0, bf0); PH_CLOSE();
    LDB2(0, 1, bf1);
    PH_OPEN(); MMQ(0, 1, bf1); PH_CLOSE();
    LDA4(0, 1);
    PH_OPEN(); MMQ(1, 1, bf1); PH_CLOSE();
    SBAR();
    __builtin_amdgcn_s_setprio(1);
    MMQ(1, 0, bf0);
    __builtin_amdgcn_s_setprio(0);
    VM(0); // drains tile15 (>=4 phases cover)
    SBAR();
    LDA4(1, 0);
    LDB2(1, 0, bf0);
    PH_OPEN(); MMQ(0, 0, bf0); PH_CLOSE();
    LDB2(1, 1, bf1);
    PH_OPEN(); MMQ(0, 1, bf1); PH_CLOSE();
    LDA4(1, 1);
    PH_OPEN(); MMQ(1, 1, bf1); PH_CLOSE();
    SBAR();
    MMQ(1, 0, bf0);
    SBAR();
  }

  const int rq = q * 4;
  if constexpr (SMODE == 0) {
    // coalesced fp32 epilogue: 4 quarters of 64 rows staged in LDS (stride 266,
    // <=2-way banks both sides), then full-line float4 stores.
    float* Cf = (float*)Cp + cStrideZ * z;
    float* smF = (float*)sm;
    const int r0s = t >> 3;      // 0..63
    const int c0s = (t & 7) * 4; // cols c0s + 32j
#pragma unroll
    for (int qt = 0; qt < 4; ++qt) {
      if (wm == (qt >> 1)) {
        const int mb = (qt & 1) * 4;
#pragma unroll
        for (int m2 = 0; m2 < 4; ++m2)
#pragma unroll
          for (int n = 0; n < 4; ++n)
#pragma unroll
            for (int r = 0; r < 4; ++r)
              smF[(m2 * 16 + rq + r) * 266 + wn * 64 + n * 16 + fr] = acc[mb + m2][n][r];
      }
      __syncthreads();
#pragma unroll
      for (int j = 0; j < 8; ++j) {
        const int col = c0s + j * 32;
        const float4 val = *(const float4*)&smF[r0s * 266 + col];
        *(float4*)&Cf[(long)(rowBase + qt * 64 + r0s) * 1024 + colBase + col] = val;
      }
      __syncthreads();
    }
  } else {
    // swizzled C-tile in LDS (shared by both permute variants)
#pragma unroll
    for (int m = 0; m < 8; ++m)
#pragma unroll
      for (int n = 0; n < 4; ++n)
#pragma unroll
        for (int r = 0; r < 4; ++r) {
          const int row = wm * 128 + m * 16 + rq + r;
          const int col = wn * 64 + n * 16 + fr;
          sm[row * 256 + (((col >> 3) ^ (row & 7)) * 8) + (col & 7)] = f2bf(acc[m][n][r]);
        }
    __syncthreads();
    ushort_t* Cb = (ushort_t*)Cp + cStrideZ * z;
    if (z != vzsel) {
      // proj-permute: row grow = b*4096 + s, s = l*16+h -> (b*16+h)*256 + l
      const int cc = t & 31;
      const int r0 = t >> 5;
#pragma unroll
      for (int i = 0; i < 16; ++i) {
        const int row = r0 + i * 16;
        const uint4 val = *(const uint4*)(sm + row * 256 + ((cc ^ (row & 7)) * 8));
        const int grow = rowBase + row;
        const int b = grow >> 12;
        const int s = grow & 4095;
        const int orow = ((b << 4) + (s & 15)) * 256 + (s >> 4);
        *(uint4*)(Cb + (long)orow * 1024 + colBase + cc * 8) = val;
      }
    } else {
      // V transposed store: vhT2[bh][lblk][d][l16]; tile covers one lblk.
      const int bq = rowBase >> 12;
      const int lblk = (rowBase & 4095) >> 8;
      ushort_t* base0 = Cb + (long)lblk * 16384;
#pragma unroll
      for (int i = 0; i < 8; ++i) {
        const int cid = i * 512 + t; // d fast, h slow -> coalesced stores
        const int d = cid & 255;
        const int h = cid >> 8;
        uint_t w[8];
#pragma unroll
        for (int j = 0; j < 8; ++j) {
          const int r0 = (2 * j) * 16 + h;
          const int r1 = (2 * j + 1) * 16 + h;
          const ushort_t v0 = sm[r0 * 256 + (((d >> 3) ^ (r0 & 7)) * 8) + (d & 7)];
          const ushort_t v1 = sm[r1 * 256 + (((d >> 3) ^ (r1 & 7)) * 8) + (d & 7)];
          w[j] = (uint_t)v0 | ((uint_t)v1 << 16);
        }
        ushort_t* dst = base0 + (long)(bq * 16 + h) * 262144 + (colBase + d) * 16;
        *(uint4*)dst = make_uint4(w[0], w[1], w[2], w[3]);
        *(uint4*)(dst + 8) = make_uint4(w[4], w[5], w[6], w[7]);
      }
    }
  }
#undef STAGE
#undef LDA4
#undef LDB2
#undef MMQ
}

extern "C" void kernel_launch(void* const* d_in, const int* in_sizes, int n_in,
                              void* d_out, int out_size, void* d_ws, size_t ws_size,
                              hipStream_t stream) {
  const float* q = (const float*)d_in[0];
  const float* k = (const float*)d_in[1];
  const float* v = (const float*)d_in[2];
  const int* mask = (const int*)d_in[3];
  const float* Wq = (const float*)d_in[4];
  const float* Wk = (const float*)d_in[5];
  const float* Wv = (const float*)d_in[6];
  const float* Wo = (const float*)d_in[7];
  float* out = (float*)d_out;

  char* ws = (char*)d_ws;
  const size_t MB = 1024 * 1024;
  ushort_t* WT = (ushort_t*)ws; // packed [4][1024][1024] bf16: Wq,Wk,Wv,Wo (8MB)

  const bool big = ws_size >= (size_t)200 * MB;

  if (big) {
    // layout: WT 0..8 | qkvb 8..104 | qh 104..136 | kh 136..168 | vhT2 168..200
    // after proj (qkvb dead): x 48..80
    ushort_t* qkvb = (ushort_t*)(ws + 8 * MB);
    ushort_t* qh = (ushort_t*)(ws + 104 * MB);
    ushort_t* kh = (ushort_t*)(ws + 136 * MB);
    ushort_t* vhT2 = (ushort_t*)(ws + 168 * MB);
    ushort_t* x = (ushort_t*)(ws + 48 * MB);

    prep<<<28672, 256, 0, stream>>>(q, k, v, Wq, Wk, Wv, Wo, (uint4*)qkvb, WT);
    // one batched dispatch: z=0/1 -> qh/kh proj-permute; z=2 -> vhT2 transposed
    gemm256<1><<<768, 512, 0, stream>>>(qkvb, qkvb + (size_t)16777216,
                                        qkvb + (size_t)33554432, WT, qh, 1 << 20,
                                        (long)16777216, 2);
    attn_fused<<<256, 512, 0, stream>>>(qh, kh, vhT2, mask, x);
    gemm256<0><<<256, 512, 0, stream>>>(x, x, x, WT + (size_t)3145728, out, 0, 0, -1);
  } else {
    // serial fallback (peak 168MB): WT 0..8 | qb 8..40 | qh 40..72 | kh 72..104
    // | vhT2 104..136 ; after proj: x 16..48
    ushort_t* qb = (ushort_t*)(ws + 8 * MB);
    ushort_t* qh = (ushort_t*)(ws + 40 * MB);
    ushort_t* kh = (ushort_t*)(ws + 72 * MB);
    ushort_t* vhT2 = (ushort_t*)(ws + 104 * MB);
    ushort_t* x = (ushort_t*)(ws + 16 * MB);

    transpose_w4<<<dim3(32, 32, 4), 256, 0, stream>>>(Wq, Wk, Wv, Wo, WT);
    cvt1<<<8192, 256, 0, stream>>>((const float4*)q, (uint4*)qb);
    gemm256<1><<<256, 512, 0, stream>>>(qb, qb, qb, WT, qh, 0, 0, -1);
    cvt1<<<8192, 256, 0, stream>>>((const float4*)k, (uint4*)qb);
    gemm256<1><<<256, 512, 0, stream>>>(qb, qb, qb, WT + (size_t)1048576, kh, 0, 0, -1);
    cvt1<<<8192, 256, 0, stream>>>((const float4*)v, (uint4*)qb);
    gemm256<1><<<256, 512, 0, stream>>>(qb, qb, qb, WT + (size_t)2097152, vhT2, 0, 0, 0);
    attn_fused<<<256, 512, 0, stream>>>(qh, kh, vhT2, mask, x);
    gemm256<0><<<256, 512, 0, stream>>>(x, x, x, WT + (size_t)3145728, out, 0, 0, -1);
  }
}